// Round 2
// 126.283 us; speedup vs baseline: 1.0602x; 1.0602x over previous
//
#include <hip/hip_runtime.h>

#define NBINS 229
#define OUTF  88
#define MODEL 128
#define WSZ   30
#define WIN   61
#define TLEN  1024
#define BT    4096

#define NC1 648      // gemm1 real cols
#define NP1 704      // gemm1 padded cols (11*64)
#define NC2 216      // combine-gemm real cols

typedef short bf16x8 __attribute__((ext_vector_type(8)));
typedef float f32x4 __attribute__((ext_vector_type(4)));
typedef unsigned short ushort_t;

__device__ __forceinline__ float sigmoid_f(float x) {
    return __builtin_amdgcn_rcpf(1.f + __expf(-x));
}
__device__ __forceinline__ ushort_t f2bf(float f) {
    unsigned u = __float_as_uint(f);
    return (ushort_t)((u + 0x7fffu + ((u >> 16) & 1u)) >> 16);
}

// 8-term tanh-trick partial: sum v[d]*rcp(EH[d]*EP[d]+1), EP packed bf16 pairs
__device__ __forceinline__ float dot8(uint4 pv, float4 ha, float4 hb,
                                      float4 va, float4 vb) {
    float r;
    r  = va.x * __builtin_amdgcn_rcpf(__builtin_fmaf(ha.x, __uint_as_float(pv.x << 16), 1.f));
    r += va.y * __builtin_amdgcn_rcpf(__builtin_fmaf(ha.y, __uint_as_float(pv.x & 0xffff0000u), 1.f));
    r += va.z * __builtin_amdgcn_rcpf(__builtin_fmaf(ha.z, __uint_as_float(pv.y << 16), 1.f));
    r += va.w * __builtin_amdgcn_rcpf(__builtin_fmaf(ha.w, __uint_as_float(pv.y & 0xffff0000u), 1.f));
    r += vb.x * __builtin_amdgcn_rcpf(__builtin_fmaf(hb.x, __uint_as_float(pv.z << 16), 1.f));
    r += vb.y * __builtin_amdgcn_rcpf(__builtin_fmaf(hb.y, __uint_as_float(pv.z & 0xffff0000u), 1.f));
    r += vb.z * __builtin_amdgcn_rcpf(__builtin_fmaf(hb.z, __uint_as_float(pv.w << 16), 1.f));
    r += vb.w * __builtin_amdgcn_rcpf(__builtin_fmaf(hb.w, __uint_as_float(pv.w & 0xffff0000u), 1.f));
    return r;
}

// ---------------------------------------------------------------------------
// prep: build bf16 GEMM operands + fp32 biases + sv sums.
// B1b[n][k] (n-major, 704x256) column map (n):
//   [  0, 88) Wf[k][n]          [ 88,216) Wao[k][n-88]
//   [216,344) Wao[k+229][n-216] [344,472) Wac[k+176][n-344]
//   [472,560) Wl1[k][n-472]     [560,648) Wlc[k+176][n-560]
// B2b[n][k] (256x192): [0,128) Wac[k][n]; [128,216) Wlc[k][n-128]; pad 0
// specB[4096][256] bf16 row-major (k>=229 zero)
// bias1: [0,88)=bf, [88,216)=bao, else 0 ; bias2: [0,128)=bac, else 0
// sv[0]=sum(vo), sv[1]=sum(vc)
// ---------------------------------------------------------------------------
#define PREP_BLOCKS 1925

__global__ __launch_bounds__(256) void prep_kernel(
    const float* __restrict__ Wf,  const float* __restrict__ bfr,
    const float* __restrict__ Wao, const float* __restrict__ bao,
    const float* __restrict__ Wl1,
    const float* __restrict__ Wac, const float* __restrict__ bac,
    const float* __restrict__ Wlc,
    const float* __restrict__ spec,
    const float* __restrict__ vo, const float* __restrict__ vc,
    ushort_t* __restrict__ B1b, ushort_t* __restrict__ B2b,
    ushort_t* __restrict__ specB,
    float* __restrict__ bias1, float* __restrict__ bias2,
    float* __restrict__ sv)
{
    __shared__ float red[4];
    const int b = blockIdx.x;
    if (b < 704) {                                  // B1b
        int idx = b * 256 + threadIdx.x;
        int n = idx >> 8, k = idx & 255;
        float v = 0.f;
        if (k < NBINS && n < NC1) {
            if (n < 88)       v = Wf[k * 88 + n];
            else if (n < 216) v = Wao[k * MODEL + (n - 88)];
            else if (n < 344) v = Wao[(k + NBINS) * MODEL + (n - 216)];
            else if (n < 472) v = Wac[(k + 176) * MODEL + (n - 344)];
            else if (n < 560) v = Wl1[k * 88 + (n - 472)];
            else              v = Wlc[(k + 176) * 88 + (n - 560)];
        }
        B1b[idx] = f2bf(v);
    } else if (b < 896) {                           // B2b
        int idx = (b - 704) * 256 + threadIdx.x;
        int n = idx / 192, k = idx - n * 192;
        float v = 0.f;
        if (k < 176 && n < NC2)
            v = (n < 128) ? Wac[k * MODEL + n] : Wlc[k * 88 + (n - 128)];
        B2b[idx] = f2bf(v);
    } else if (b < 1920) {                          // specB, 4 elems/thread
        int idx = (b - 896) * 256 + threadIdx.x;
        int r = idx >> 6, k4 = (idx & 63) * 4;
        const float* sp = spec + (size_t)r * NBINS;
        ushort4 o;
        o.x = (k4 + 0 < NBINS) ? f2bf(sp[k4 + 0]) : (ushort_t)0;
        o.y = (k4 + 1 < NBINS) ? f2bf(sp[k4 + 1]) : (ushort_t)0;
        o.z = (k4 + 2 < NBINS) ? f2bf(sp[k4 + 2]) : (ushort_t)0;
        o.w = (k4 + 3 < NBINS) ? f2bf(sp[k4 + 3]) : (ushort_t)0;
        *(ushort4*)&specB[(size_t)r * 256 + k4] = o;
    } else if (b < 1924) {                          // biases
        int idx = (b - 1920) * 256 + threadIdx.x;
        if (idx < 704)
            bias1[idx] = (idx < 88) ? bfr[idx] : (idx < 216 ? bao[idx - 88] : 0.f);
        else if (idx < 960) {
            int n = idx - 704;
            bias2[n] = (n < 128) ? bac[n] : 0.f;
        }
    } else {                                        // sv sums
        int wid = threadIdx.x >> 6, lane = threadIdx.x & 63;
        const float* vp = (wid < 2) ? vo : vc;
        float val = vp[(wid & 1) * 64 + lane];
#pragma unroll
        for (int m = 32; m; m >>= 1) val += __shfl_xor(val, m, 64);
        if (lane == 0) red[wid] = val;
        __syncthreads();
        if (threadIdx.x == 0) {
            sv[0] = red[0] + red[1];
            sv[1] = red[2] + red[3];
        }
    }
}

// ---------------------------------------------------------------------------
// MFMA bf16 GEMM1, no LDS; wave tile 16m x 64n, block 64m x 64n (4 waves).
// XCD swizzle: e=flat&7 -> rows [512e,512e+512) on XCD e (RTS=3).
// Epilogue by column n:
//   n<88: feat fp32 | 88..216: EHo=exp(2v) fp32 | 216..344: EPo bf16
//   344..472: EPc bf16 (both exp'd) | 472..560: Rb bf16 | 560..648: Qb bf16
// ---------------------------------------------------------------------------
template<int KITER, int RTS>
__global__ __launch_bounds__(256) void gemm_mfma(
    const ushort_t* __restrict__ Ab, int lka,
    const ushort_t* __restrict__ Bb,
    const float* __restrict__ bias, int Nc,
    float* __restrict__ feat, float* __restrict__ EHo_,
    ushort_t* __restrict__ EPo_, ushort_t* __restrict__ EPc_,
    ushort_t* __restrict__ Rb_, ushort_t* __restrict__ Qb_)
{
    const int tid = threadIdx.x;
    const int wv = tid >> 6, ln = tid & 63;
    const int l15 = ln & 15, qd = ln >> 4;
    const int flat = blockIdx.y * gridDim.x + blockIdx.x;
    const int e = flat & 7, kf = flat >> 3;
    const int rb = (e * (1 << RTS) + (kf & ((1 << RTS) - 1))) * 64;
    const int cb = (kf >> RTS) * 64;
    const int lkb = KITER * 32;

    const ushort_t* ap = Ab + (size_t)(rb + wv * 16 + l15) * lka + qd * 8;
    const ushort_t* bp[4];
#pragma unroll
    for (int nt = 0; nt < 4; nt++)
        bp[nt] = Bb + (size_t)(cb + nt * 16 + l15) * lkb + qd * 8;

    f32x4 acc[4];
#pragma unroll
    for (int nt = 0; nt < 4; nt++) acc[nt] = (f32x4){0.f, 0.f, 0.f, 0.f};

    bf16x8 af = *(const bf16x8*)ap, bfv[4];
#pragma unroll
    for (int nt = 0; nt < 4; nt++) bfv[nt] = *(const bf16x8*)bp[nt];

    for (int it = 0; it < KITER; it++) {
        bf16x8 an, bn[4];
        const int nk = (it + 1 < KITER) ? (it + 1) * 32 : 0;
        an = *(const bf16x8*)(ap + nk);
#pragma unroll
        for (int nt = 0; nt < 4; nt++) bn[nt] = *(const bf16x8*)(bp[nt] + nk);
#pragma unroll
        for (int nt = 0; nt < 4; nt++)
            acc[nt] = __builtin_amdgcn_mfma_f32_16x16x32_bf16(
                af, bfv[nt], acc[nt], 0, 0, 0);
        af = an;
#pragma unroll
        for (int nt = 0; nt < 4; nt++) bfv[nt] = bn[nt];
    }

    const int mbase = rb + wv * 16 + qd * 4;
#pragma unroll
    for (int nt = 0; nt < 4; nt++) {
        const int n = cb + nt * 16 + l15;
        if (n < Nc) {
            const float bn = bias[n];
#pragma unroll
            for (int r = 0; r < 4; r++) {
                const int m = mbase + r;
                float val = acc[nt][r] + bn;
                if (n < 88) {
                    feat[(size_t)m * 88 + n] = val;
                } else if (n < 216) {
                    EHo_[(size_t)m * 128 + (n - 88)] = __expf(val + val);
                } else if (n < 344) {
                    EPo_[(size_t)m * 128 + (n - 216)] = f2bf(__expf(val + val));
                } else if (n < 472) {
                    EPc_[(size_t)m * 128 + (n - 344)] = f2bf(__expf(val + val));
                } else if (n < 560) {
                    Rb_[(size_t)m * 96 + (n - 472)] = f2bf(val);
                } else {
                    Qb_[(size_t)m * 96 + (n - 560)] = f2bf(val);
                }
            }
        }
    }
}

// ---------------------------------------------------------------------------
// Fused attention: attn1 (onset) + combine-GEMM + attn2 (frame) in one kernel.
// One wave per position, 8 positions / 512-thread block, XCD-swizzled.
// The chain onset_pred -> C2 -> frame attention is ROW-LOCAL: position s needs
// only xB[s] = [feat[s], onset_pred[s]], so the whole combine stack runs
// per-block with no global round-trip.
//   Phase A: onset attention (EHo global s_load, EPo/Rb windows in LDS);
//            writes a_onset + onset_pred, deposits bf16 x-row into Xb LDS.
//   Phase B: C2 = Xb @ B2 via MFMA (16x224 tile, K=192, B2 read once/block
//            from L2); n<128 -> EHc=exp(2v) LDS fp32; 128..216 -> basec LDS.
//   Phase C: frame attention (EHc from LDS broadcast), writes a_frame+frame.
// ---------------------------------------------------------------------------
#define EPST 136
#define RST  96
#define XST  200   // 400B row stride: 16B-aligned, rows spread over 8 banks

__global__ __launch_bounds__(512) void attn_fused(
    const float* __restrict__ EHo,
    const ushort_t* __restrict__ EPo_g,
    const ushort_t* __restrict__ Rb,
    const ushort_t* __restrict__ EPc_g,
    const ushort_t* __restrict__ Qb,
    const float* __restrict__ feat,          // [BT,88] fp32 (= out4)
    const ushort_t* __restrict__ B2b,        // [256,192] bf16 n-major
    const float* __restrict__ bias2,
    const float* __restrict__ vo, const float* __restrict__ vc,
    const float* __restrict__ svp,
    const float* __restrict__ bl1, const float* __restrict__ blc,
    float* __restrict__ a_o_out, float* __restrict__ onset_out,
    float* __restrict__ a_c_out, float* __restrict__ frame_out)
{
    __shared__ alignas(16) ushort_t Plo[68 * EPST];   // 18,496 B
    __shared__ alignas(16) ushort_t Rl [68 * RST];    // 13,056 B
    __shared__ alignas(16) ushort_t Plc[68 * EPST];   // 18,496 B
    __shared__ alignas(16) ushort_t Ql [68 * RST];    // 13,056 B
    __shared__ alignas(16) ushort_t Xb [16 * XST];    //  6,400 B
    __shared__ alignas(16) float    EHc[8 * 128];     //  4,096 B
    __shared__ alignas(16) float    basec[8 * 88];    //  2,816 B  (~76.4 KB)

    const int tid = threadIdx.x;
    const int s0 = ((blockIdx.x & 7) * 64 + (blockIdx.x >> 3)) * 8;
    const int t0 = s0 & (TLEN - 1);

    // stage EPo+EPc (68 rows x 128 bf16 each): pad rows = bf16(1.0) = exp(0)
    for (int i = tid; i < 68 * 16; i += 512) {
        int j = i >> 4, c = (i & 15) * 8;
        int tg = t0 + j - WSZ;
        uint4 vP = {0x3f803f80u, 0x3f803f80u, 0x3f803f80u, 0x3f803f80u};
        uint4 vC = vP;
        if ((unsigned)tg < (unsigned)TLEN) {
            vP = *(const uint4*)&EPo_g[(size_t)(s0 - WSZ + j) * 128 + c];
            vC = *(const uint4*)&EPc_g[(size_t)(s0 - WSZ + j) * 128 + c];
        }
        *(uint4*)&Plo[j * EPST + c] = vP;
        *(uint4*)&Plc[j * EPST + c] = vC;
    }
    // stage R+Q (68 rows x 96 bf16 each): pad rows = 0 (OOB contributes a*0)
    for (int i = tid; i < 68 * 12; i += 512) {
        int j = i / 12, c = (i - j * 12) * 8;
        int tg = t0 + j - WSZ;
        uint4 vR = {0u, 0u, 0u, 0u}, vQ = {0u, 0u, 0u, 0u};
        if ((unsigned)tg < (unsigned)TLEN) {
            vR = *(const uint4*)&Rb[(size_t)(s0 - WSZ + j) * 96 + c];
            vQ = *(const uint4*)&Qb[(size_t)(s0 - WSZ + j) * 96 + c];
        }
        *(uint4*)&Rl[j * RST + c] = vR;
        *(uint4*)&Ql[j * RST + c] = vQ;
    }
    // Xb: rows 0..7 cols 0..87 = feat bf16; everything else zero
    // (cols 88..175 filled by phase A; 176.. and rows 8..15 stay zero)
    for (int i = tid; i < 16 * XST; i += 512) {
        int r = i / XST, k = i - r * XST;
        ushort_t v = 0;
        if (r < 8 && k < 88) v = f2bf(feat[(size_t)(s0 + r) * 88 + k]);
        Xb[i] = v;
    }
    __syncthreads();

    const int q = tid >> 6;
    const int w = tid & 63;
    const int s = s0 + q;
    const int su = __builtin_amdgcn_readfirstlane(s);
    const int row = q + ((w < WIN) ? w : 0);

    // ---- Phase A: onset attention ----
    {
        const ushort_t* pb = &Plo[row * EPST];
        const float* hrow = EHo + (size_t)su * 128;   // uniform -> s_load
        float accr = 0.f;
#pragma unroll
        for (int d8 = 0; d8 < 16; d8++) {
            uint4 pv = *(const uint4*)(pb + d8 * 8);
            float4 ha = *(const float4*)(hrow + d8 * 8);
            float4 hb = *(const float4*)(hrow + d8 * 8 + 4);
            float4 va = *(const float4*)(vo + d8 * 8);
            float4 vb = *(const float4*)(vo + d8 * 8 + 4);
            accr += dot8(pv, ha, hb, va, vb);
        }
        float eng = svp[0] - 2.f * accr;
        if (w >= WIN) eng = -1e30f;

        float mx = eng;
#pragma unroll
        for (int m = 32; m; m >>= 1) mx = fmaxf(mx, __shfl_xor(mx, m, 64));
        float ex = __expf(eng - mx);
        float sm = ex;
#pragma unroll
        for (int m = 32; m; m >>= 1) sm += __shfl_xor(sm, m, 64);
        float a = ex * __builtin_amdgcn_rcpf(sm);
        if (w < WIN) a_o_out[(size_t)s * WIN + w] = a;

        if (w < 44) {
            const int f = 2 * w;
            float acc0 = bl1[f], acc1 = bl1[f + 1];
            const ushort_t* rr0 = &Rl[q * RST + f];
#pragma unroll
            for (int ww = 0; ww < WIN; ww++) {
                float aw = __uint_as_float(
                    __builtin_amdgcn_readlane(__float_as_uint(a), ww));
                unsigned u = *(const unsigned*)(rr0 + ww * RST);
                acc0 += aw * __uint_as_float(u << 16);
                acc1 += aw * __uint_as_float(u & 0xffff0000u);
            }
            float p0 = sigmoid_f(acc0), p1 = sigmoid_f(acc1);
            *(float2*)&onset_out[(size_t)s * OUTF + f] = make_float2(p0, p1);
            ushort2 o; o.x = f2bf(p0); o.y = f2bf(p1);
            *(ushort2*)&Xb[q * XST + 88 + f] = o;
        }
    }
    __syncthreads();

    // ---- Phase B: C2 = Xb @ B2 via MFMA; 14 n-tiles of 16 over 8 waves ----
    {
        const int l15 = w & 15, qd = w >> 4;
#pragma unroll
        for (int rt = 0; rt < 2; rt++) {
            const int t = q + rt * 8;
            if (t < 14) {
                const int n0 = t * 16;
                const ushort_t* bp = B2b + (size_t)(n0 + l15) * 192 + qd * 8;
                const ushort_t* ap = &Xb[l15 * XST + qd * 8];
                f32x4 acc = (f32x4){0.f, 0.f, 0.f, 0.f};
#pragma unroll
                for (int it = 0; it < 6; it++) {
                    bf16x8 av = *(const bf16x8*)(ap + it * 32);
                    bf16x8 bv = *(const bf16x8*)(bp + it * 32);
                    acc = __builtin_amdgcn_mfma_f32_16x16x32_bf16(
                        av, bv, acc, 0, 0, 0);
                }
                if (qd < 2) {                       // rows 0..7 are real
                    const int n = n0 + l15;
                    const float b2 = bias2[n];
#pragma unroll
                    for (int r = 0; r < 4; r++) {
                        const int m = qd * 4 + r;
                        float val = acc[r] + b2;
                        if (n < 128)        EHc[m * 128 + n] = __expf(val + val);
                        else if (n < NC2)   basec[m * 88 + (n - 128)] = val;
                    }
                }
            }
        }
    }
    __syncthreads();

    // ---- Phase C: frame attention (EH from LDS broadcast) ----
    {
        const ushort_t* pb = &Plc[row * EPST];
        const float* hl = &EHc[q * 128];
        float accr = 0.f;
#pragma unroll
        for (int d8 = 0; d8 < 16; d8++) {
            uint4 pv = *(const uint4*)(pb + d8 * 8);
            float4 ha = *(const float4*)(hl + d8 * 8);
            float4 hb = *(const float4*)(hl + d8 * 8 + 4);
            float4 va = *(const float4*)(vc + d8 * 8);
            float4 vb = *(const float4*)(vc + d8 * 8 + 4);
            accr += dot8(pv, ha, hb, va, vb);
        }
        float eng = svp[1] - 2.f * accr;
        if (w >= WIN) eng = -1e30f;

        float mx = eng;
#pragma unroll
        for (int m = 32; m; m >>= 1) mx = fmaxf(mx, __shfl_xor(mx, m, 64));
        float ex = __expf(eng - mx);
        float sm = ex;
#pragma unroll
        for (int m = 32; m; m >>= 1) sm += __shfl_xor(sm, m, 64);
        float a = ex * __builtin_amdgcn_rcpf(sm);
        if (w < WIN) a_c_out[(size_t)s * WIN + w] = a;

        if (w < 44) {
            const int f = 2 * w;
            float acc0 = blc[f]     + basec[q * 88 + f];
            float acc1 = blc[f + 1] + basec[q * 88 + f + 1];
            const ushort_t* rr0 = &Ql[q * RST + f];
#pragma unroll
            for (int ww = 0; ww < WIN; ww++) {
                float aw = __uint_as_float(
                    __builtin_amdgcn_readlane(__float_as_uint(a), ww));
                unsigned u = *(const unsigned*)(rr0 + ww * RST);
                acc0 += aw * __uint_as_float(u << 16);
                acc1 += aw * __uint_as_float(u & 0xffff0000u);
            }
            float p0 = sigmoid_f(acc0), p1 = sigmoid_f(acc1);
            *(float2*)&frame_out[(size_t)s * OUTF + f] = make_float2(p0, p1);
        }
    }
}

// ---------------------------------------------------------------------------
extern "C" void kernel_launch(void* const* d_in, const int* in_sizes, int n_in,
                              void* d_out, int out_size, void* d_ws, size_t ws_size,
                              hipStream_t stream)
{
    const float* spec = (const float*)d_in[0];
    const float* Wf   = (const float*)d_in[1];
    const float* bf_  = (const float*)d_in[2];
    const float* Wao  = (const float*)d_in[3];
    const float* bao  = (const float*)d_in[4];
    const float* vo   = (const float*)d_in[5];
    const float* Wl1  = (const float*)d_in[6];
    const float* bl1  = (const float*)d_in[7];
    const float* Wac  = (const float*)d_in[8];
    const float* bac  = (const float*)d_in[9];
    const float* vc   = (const float*)d_in[10];
    const float* Wlc  = (const float*)d_in[11];
    const float* blc  = (const float*)d_in[12];

    float* out  = (float*)d_out;
    float* out0 = out;                 // frame_pred [BT,88]
    float* out1 = out + 360448;        // a_frame    [BT,61]
    float* out2 = out + 610304;        // onset_pred [BT,88]
    float* out3 = out + 970752;        // a_onset    [BT,61]
    float* out4 = out + 1220608;       // feat_pred  [BT,88]

    // Workspace layout (float offsets; u16 arrays occupy count/2 floats):
    //   sv      @ 0        (16)
    //   bias1   @ 16       (704)
    //   bias2   @ 720      (256)
    //   B1b u16 @ 976      (704*256 u16  = 90112 f)   -> ends 91088
    //   B2b u16 @ 91088    (256*192 u16  = 24576 f)   -> ends 115664
    //   specB   @ 115664   (4096*256 u16 = 524288 f)  -> ends 639952
    //   EHo f32 @ 639952   (4096*128 f32 = 524288 f)  -> ends 1164240
    //   EPo u16 @ 1164240  (4096*128 u16 = 262144 f)  -> ends 1426384
    //   EPc u16 @ 1426384  (262144 f)                 -> ends 1688528
    //   Rb  u16 @ 1688528  (4096*96 u16  = 196608 f)  -> ends 1885136
    //   Qb  u16 @ 1885136  (196608 f)                 -> ends 2081744 (~8.3MB)
    float* ws = (float*)d_ws;
    float*    sv    = ws;
    float*    bias1 = ws + 16;
    float*    bias2 = ws + 720;
    ushort_t* B1b   = (ushort_t*)(ws + 976);
    ushort_t* B2b   = (ushort_t*)(ws + 91088);
    ushort_t* specB = (ushort_t*)(ws + 115664);
    float*    EHo   = ws + 639952;
    ushort_t* EPo   = (ushort_t*)(ws + 1164240);
    ushort_t* EPc   = (ushort_t*)(ws + 1426384);
    ushort_t* Rb    = (ushort_t*)(ws + 1688528);
    ushort_t* Qb    = (ushort_t*)(ws + 1885136);
    (void)ws_size; (void)in_sizes; (void)n_in; (void)out_size;

    prep_kernel<<<PREP_BLOCKS, 256, 0, stream>>>(
        Wf, bf_, Wao, bao, Wl1, Wac, bac, Wlc, spec, vo, vc,
        B1b, B2b, specB, bias1, bias2, sv);

    gemm_mfma<8, 3><<<dim3(NP1 / 64, 64), 256, 0, stream>>>(
        specB, 256, B1b, bias1, NC1, out4, EHo, EPo, EPc, Rb, Qb);

    attn_fused<<<BT / 8, 512, 0, stream>>>(
        EHo, EPo, Rb, EPc, Qb, out4, B2b, bias2, vo, vc, sv, bl1, blc,
        out3, out2, out1, out0);
}

// Round 3
// 123.529 us; speedup vs baseline: 1.0838x; 1.0223x over previous
//
#include <hip/hip_runtime.h>

#define NBINS 229
#define OUTF  88
#define MODEL 128
#define WSZ   30
#define WIN   61
#define TLEN  1024
#define BT    4096

#define NC1 648      // gemm1 real cols
#define NP1 704      // gemm1 padded cols (11*64)
#define NC2 216      // combine-gemm real cols

typedef short bf16x8 __attribute__((ext_vector_type(8)));
typedef float f32x4 __attribute__((ext_vector_type(4)));
typedef unsigned short ushort_t;

__device__ __forceinline__ float sigmoid_f(float x) {
    return __builtin_amdgcn_rcpf(1.f + __expf(-x));
}
__device__ __forceinline__ ushort_t f2bf(float f) {
    unsigned u = __float_as_uint(f);
    return (ushort_t)((u + 0x7fffu + ((u >> 16) & 1u)) >> 16);
}

// 8-term tanh-trick partial: sum v[d]*rcp(EH[d]*EP[d]+1), EP packed bf16 pairs
__device__ __forceinline__ float dot8(uint4 pv, float4 ha, float4 hb,
                                      float4 va, float4 vb) {
    float r;
    r  = va.x * __builtin_amdgcn_rcpf(__builtin_fmaf(ha.x, __uint_as_float(pv.x << 16), 1.f));
    r += va.y * __builtin_amdgcn_rcpf(__builtin_fmaf(ha.y, __uint_as_float(pv.x & 0xffff0000u), 1.f));
    r += va.z * __builtin_amdgcn_rcpf(__builtin_fmaf(ha.z, __uint_as_float(pv.y << 16), 1.f));
    r += va.w * __builtin_amdgcn_rcpf(__builtin_fmaf(ha.w, __uint_as_float(pv.y & 0xffff0000u), 1.f));
    r += vb.x * __builtin_amdgcn_rcpf(__builtin_fmaf(hb.x, __uint_as_float(pv.z << 16), 1.f));
    r += vb.y * __builtin_amdgcn_rcpf(__builtin_fmaf(hb.y, __uint_as_float(pv.z & 0xffff0000u), 1.f));
    r += vb.z * __builtin_amdgcn_rcpf(__builtin_fmaf(hb.z, __uint_as_float(pv.w << 16), 1.f));
    r += vb.w * __builtin_amdgcn_rcpf(__builtin_fmaf(hb.w, __uint_as_float(pv.w & 0xffff0000u), 1.f));
    return r;
}

// ---------------------------------------------------------------------------
// prep: build bf16 GEMM weight operands + fp32 biases + sv sums.
// (specB is GONE: gemm1 now converts spec fp32 -> bf16 in registers;
//  B1b's k>=229 zero-padding makes A garbage beyond 229 harmless.)
// B1b[n][k] (n-major, 704x256) column map (n):
//   [  0, 88) Wf[k][n]          [ 88,216) Wao[k][n-88]
//   [216,344) Wao[k+229][n-216] [344,472) Wac[k+176][n-344]
//   [472,560) Wl1[k][n-472]     [560,648) Wlc[k+176][n-560]
// B2b[n][k] (256x192): [0,128) Wac[k][n]; [128,216) Wlc[k][n-128]; pad 0
// bias1: [0,88)=bf, [88,216)=bao, else 0 ; bias2: [0,128)=bac, else 0
// sv[0]=sum(vo), sv[1]=sum(vc)
// ---------------------------------------------------------------------------
#define PREP_BLOCKS 901

__global__ __launch_bounds__(256) void prep_kernel(
    const float* __restrict__ Wf,  const float* __restrict__ bfr,
    const float* __restrict__ Wao, const float* __restrict__ bao,
    const float* __restrict__ Wl1,
    const float* __restrict__ Wac, const float* __restrict__ bac,
    const float* __restrict__ Wlc,
    const float* __restrict__ vo, const float* __restrict__ vc,
    ushort_t* __restrict__ B1b, ushort_t* __restrict__ B2b,
    float* __restrict__ bias1, float* __restrict__ bias2,
    float* __restrict__ sv)
{
    __shared__ float red[4];
    const int b = blockIdx.x;
    if (b < 704) {                                  // B1b
        int idx = b * 256 + threadIdx.x;
        int n = idx >> 8, k = idx & 255;
        float v = 0.f;
        if (k < NBINS && n < NC1) {
            if (n < 88)       v = Wf[k * 88 + n];
            else if (n < 216) v = Wao[k * MODEL + (n - 88)];
            else if (n < 344) v = Wao[(k + NBINS) * MODEL + (n - 216)];
            else if (n < 472) v = Wac[(k + 176) * MODEL + (n - 344)];
            else if (n < 560) v = Wl1[k * 88 + (n - 472)];
            else              v = Wlc[(k + 176) * 88 + (n - 560)];
        }
        B1b[idx] = f2bf(v);
    } else if (b < 896) {                           // B2b
        int idx = (b - 704) * 256 + threadIdx.x;
        int n = idx / 192, k = idx - n * 192;
        float v = 0.f;
        if (k < 176 && n < NC2)
            v = (n < 128) ? Wac[k * MODEL + n] : Wlc[k * 88 + (n - 128)];
        B2b[idx] = f2bf(v);
    } else if (b < 900) {                           // biases
        int idx = (b - 896) * 256 + threadIdx.x;
        if (idx < 704)
            bias1[idx] = (idx < 88) ? bfr[idx] : (idx < 216 ? bao[idx - 88] : 0.f);
        else if (idx < 960) {
            int n = idx - 704;
            bias2[n] = (n < 128) ? bac[n] : 0.f;
        }
    } else {                                        // sv sums
        int wid = threadIdx.x >> 6, lane = threadIdx.x & 63;
        const float* vp = (wid < 2) ? vo : vc;
        float val = vp[(wid & 1) * 64 + lane];
#pragma unroll
        for (int m = 32; m; m >>= 1) val += __shfl_xor(val, m, 64);
        if (lane == 0) red[wid] = val;
        __syncthreads();
        if (threadIdx.x == 0) {
            sv[0] = red[0] + red[1];
            sv[1] = red[2] + red[3];
        }
    }
}

// ---------------------------------------------------------------------------
// MFMA bf16 GEMM1, no LDS; wave tile 16m x 64n, block 64m x 64n (4 waves).
// A = spec fp32, converted to bf16 in registers (no specB staging buffer).
// k in [229,256) is garbage/zero in A but B1b is zero there -> no effect.
// XCD swizzle: e=flat&7 -> rows [512e,512e+512) on XCD e (RTS=3).
// Epilogue by column n:
//   n<88: feat fp32 | 88..216: EHo=exp(2v) fp32 | 216..344: EPo bf16
//   344..472: EPc bf16 (both exp'd) | 472..560: Rb bf16 | 560..648: Qb bf16
// ---------------------------------------------------------------------------
__device__ __forceinline__ bf16x8 cvt8(f32x4 a, f32x4 b) {
    bf16x8 r;
    r[0] = (short)f2bf(a.x); r[1] = (short)f2bf(a.y);
    r[2] = (short)f2bf(a.z); r[3] = (short)f2bf(a.w);
    r[4] = (short)f2bf(b.x); r[5] = (short)f2bf(b.y);
    r[6] = (short)f2bf(b.z); r[7] = (short)f2bf(b.w);
    return r;
}
// spec rows are only 4B-aligned (229 floats) -> memcpy keeps align-4 loads
__device__ __forceinline__ bf16x8 loadA(const float* sp, int k0) {
    if (k0 > 228) return (bf16x8)(short)0;          // it=7, qd>=1: all pad
    f32x4 a, b;
    __builtin_memcpy(&a, sp + k0, 16);
    if (k0 <= 216) {
        __builtin_memcpy(&b, sp + k0 + 4, 16);
    } else {                                        // k0==224: valid 224..228
        b = (f32x4){sp[228], 0.f, 0.f, 0.f};
    }
    return cvt8(a, b);
}

template<int KITER, int RTS>
__global__ __launch_bounds__(256) void gemm_mfma(
    const float* __restrict__ spec,
    const ushort_t* __restrict__ Bb,
    const float* __restrict__ bias, int Nc,
    float* __restrict__ feat, float* __restrict__ EHo_,
    ushort_t* __restrict__ EPo_, ushort_t* __restrict__ EPc_,
    ushort_t* __restrict__ Rb_, ushort_t* __restrict__ Qb_)
{
    const int tid = threadIdx.x;
    const int wv = tid >> 6, ln = tid & 63;
    const int l15 = ln & 15, qd = ln >> 4;
    const int flat = blockIdx.y * gridDim.x + blockIdx.x;
    const int e = flat & 7, kf = flat >> 3;
    const int rb = (e * (1 << RTS) + (kf & ((1 << RTS) - 1))) * 64;
    const int cb = (kf >> RTS) * 64;
    const int lkb = KITER * 32;

    const float* sp = spec + (size_t)(rb + wv * 16 + l15) * NBINS;
    const ushort_t* bp[4];
#pragma unroll
    for (int nt = 0; nt < 4; nt++)
        bp[nt] = Bb + (size_t)(cb + nt * 16 + l15) * lkb + qd * 8;

    f32x4 acc[4];
#pragma unroll
    for (int nt = 0; nt < 4; nt++) acc[nt] = (f32x4){0.f, 0.f, 0.f, 0.f};

    bf16x8 af = loadA(sp, qd * 8), bfv[4];
#pragma unroll
    for (int nt = 0; nt < 4; nt++) bfv[nt] = *(const bf16x8*)bp[nt];

    for (int it = 0; it < KITER; it++) {
        bf16x8 an, bn[4];
        const int nk = (it + 1 < KITER) ? (it + 1) * 32 : 0;
        an = loadA(sp, nk + qd * 8);
#pragma unroll
        for (int nt = 0; nt < 4; nt++) bn[nt] = *(const bf16x8*)(bp[nt] + nk);
#pragma unroll
        for (int nt = 0; nt < 4; nt++)
            acc[nt] = __builtin_amdgcn_mfma_f32_16x16x32_bf16(
                af, bfv[nt], acc[nt], 0, 0, 0);
        af = an;
#pragma unroll
        for (int nt = 0; nt < 4; nt++) bfv[nt] = bn[nt];
    }

    const int mbase = rb + wv * 16 + qd * 4;
#pragma unroll
    for (int nt = 0; nt < 4; nt++) {
        const int n = cb + nt * 16 + l15;
        if (n < Nc) {
            const float bn = bias[n];
#pragma unroll
            for (int r = 0; r < 4; r++) {
                const int m = mbase + r;
                float val = acc[nt][r] + bn;
                if (n < 88) {
                    feat[(size_t)m * 88 + n] = val;
                } else if (n < 216) {
                    EHo_[(size_t)m * 128 + (n - 88)] = __expf(val + val);
                } else if (n < 344) {
                    EPo_[(size_t)m * 128 + (n - 216)] = f2bf(__expf(val + val));
                } else if (n < 472) {
                    EPc_[(size_t)m * 128 + (n - 344)] = f2bf(__expf(val + val));
                } else if (n < 560) {
                    Rb_[(size_t)m * 96 + (n - 472)] = f2bf(val);
                } else {
                    Qb_[(size_t)m * 96 + (n - 560)] = f2bf(val);
                }
            }
        }
    }
}

// ---------------------------------------------------------------------------
// Fused attention: attn1 (onset) + combine-GEMM + attn2 (frame) in one kernel.
// One wave per position, 8 positions / 512-thread block, XCD-swizzled.
//   Phase A: onset attention (EHo global s_load, EPo/Rb windows in LDS);
//            writes a_onset + onset_pred, deposits bf16 x-row into Xb LDS.
//   Phase B: C2 = Xb @ B2 via MFMA; n<128 -> EHc LDS fp32; else basec LDS.
//   Phase C: frame attention (EHc from LDS broadcast), writes a_frame+frame.
// Plo/Plc use a chunk-XOR swizzle keyed on (row>>3)&7: the 8-way-conflicting
// lane set {w, w+8, ...} shares row&7 but spans 8 consecutive row>>3 values,
// so XORing the 16B-chunk index by (row>>3)&7 de-aliases it (bank conflicts
// on the 32 ds_read_b128/wave drop 8-way -> 1-way). Chunk 16 is pad, unread.
// ---------------------------------------------------------------------------
#define EPST 136
#define RST  96
#define XST  200   // 400B row stride: 16B-aligned, rows spread over 8 banks

__global__ __launch_bounds__(512) void attn_fused(
    const float* __restrict__ EHo,
    const ushort_t* __restrict__ EPo_g,
    const ushort_t* __restrict__ Rb,
    const ushort_t* __restrict__ EPc_g,
    const ushort_t* __restrict__ Qb,
    const float* __restrict__ feat,          // [BT,88] fp32 (= out4)
    const ushort_t* __restrict__ B2b,        // [256,192] bf16 n-major
    const float* __restrict__ bias2,
    const float* __restrict__ vo, const float* __restrict__ vc,
    const float* __restrict__ svp,
    const float* __restrict__ bl1, const float* __restrict__ blc,
    float* __restrict__ a_o_out, float* __restrict__ onset_out,
    float* __restrict__ a_c_out, float* __restrict__ frame_out)
{
    __shared__ alignas(16) ushort_t Plo[68 * EPST];   // 18,496 B
    __shared__ alignas(16) ushort_t Rl [68 * RST];    // 13,056 B
    __shared__ alignas(16) ushort_t Plc[68 * EPST];   // 18,496 B
    __shared__ alignas(16) ushort_t Ql [68 * RST];    // 13,056 B
    __shared__ alignas(16) ushort_t Xb [16 * XST];    //  6,400 B
    __shared__ alignas(16) float    EHc[8 * 128];     //  4,096 B
    __shared__ alignas(16) float    basec[8 * 88];    //  2,816 B  (~76.4 KB)

    const int tid = threadIdx.x;
    const int s0 = ((blockIdx.x & 7) * 64 + (blockIdx.x >> 3)) * 8;
    const int t0 = s0 & (TLEN - 1);

    // stage EPo+EPc (68 rows x 128 bf16 each): pad rows = bf16(1.0) = exp(0)
    for (int i = tid; i < 68 * 16; i += 512) {
        int j = i >> 4, c = (i & 15) * 8;
        int cs = ((i & 15) ^ ((j >> 3) & 7)) * 8;     // swizzled chunk
        int tg = t0 + j - WSZ;
        uint4 vP = {0x3f803f80u, 0x3f803f80u, 0x3f803f80u, 0x3f803f80u};
        uint4 vC = vP;
        if ((unsigned)tg < (unsigned)TLEN) {
            vP = *(const uint4*)&EPo_g[(size_t)(s0 - WSZ + j) * 128 + c];
            vC = *(const uint4*)&EPc_g[(size_t)(s0 - WSZ + j) * 128 + c];
        }
        *(uint4*)&Plo[j * EPST + cs] = vP;
        *(uint4*)&Plc[j * EPST + cs] = vC;
    }
    // stage R+Q (68 rows x 96 bf16 each): pad rows = 0 (OOB contributes a*0)
    for (int i = tid; i < 68 * 12; i += 512) {
        int j = i / 12, c = (i - j * 12) * 8;
        int tg = t0 + j - WSZ;
        uint4 vR = {0u, 0u, 0u, 0u}, vQ = {0u, 0u, 0u, 0u};
        if ((unsigned)tg < (unsigned)TLEN) {
            vR = *(const uint4*)&Rb[(size_t)(s0 - WSZ + j) * 96 + c];
            vQ = *(const uint4*)&Qb[(size_t)(s0 - WSZ + j) * 96 + c];
        }
        *(uint4*)&Rl[j * RST + c] = vR;
        *(uint4*)&Ql[j * RST + c] = vQ;
    }
    // Xb: rows 0..7 cols 0..87 = feat bf16; everything else zero
    // (cols 88..175 filled by phase A; 176.. and rows 8..15 stay zero)
    for (int i = tid; i < 16 * XST; i += 512) {
        int r = i / XST, k = i - r * XST;
        ushort_t v = 0;
        if (r < 8 && k < 88) v = f2bf(feat[(size_t)(s0 + r) * 88 + k]);
        Xb[i] = v;
    }
    __syncthreads();

    const int q = tid >> 6;
    const int w = tid & 63;
    const int s = s0 + q;
    const int su = __builtin_amdgcn_readfirstlane(s);
    const int row = q + ((w < WIN) ? w : 0);
    const int rsw = (row >> 3) & 7;

    // ---- Phase A: onset attention ----
    {
        const ushort_t* pb = &Plo[row * EPST];
        const float* hrow = EHo + (size_t)su * 128;   // uniform -> s_load
        float accr = 0.f;
#pragma unroll
        for (int d8 = 0; d8 < 16; d8++) {
            uint4 pv = *(const uint4*)(pb + ((d8 ^ rsw) << 3));
            float4 ha = *(const float4*)(hrow + d8 * 8);
            float4 hb = *(const float4*)(hrow + d8 * 8 + 4);
            float4 va = *(const float4*)(vo + d8 * 8);
            float4 vb = *(const float4*)(vo + d8 * 8 + 4);
            accr += dot8(pv, ha, hb, va, vb);
        }
        float eng = svp[0] - 2.f * accr;
        if (w >= WIN) eng = -1e30f;

        float mx = eng;
#pragma unroll
        for (int m = 32; m; m >>= 1) mx = fmaxf(mx, __shfl_xor(mx, m, 64));
        float ex = __expf(eng - mx);
        float sm = ex;
#pragma unroll
        for (int m = 32; m; m >>= 1) sm += __shfl_xor(sm, m, 64);
        float a = ex * __builtin_amdgcn_rcpf(sm);
        if (w < WIN) a_o_out[(size_t)s * WIN + w] = a;

        if (w < 44) {
            const int f = 2 * w;
            float acc0 = bl1[f], acc1 = bl1[f + 1];
            const ushort_t* rr0 = &Rl[q * RST + f];
#pragma unroll
            for (int ww = 0; ww < WIN; ww++) {
                float aw = __uint_as_float(
                    __builtin_amdgcn_readlane(__float_as_uint(a), ww));
                unsigned u = *(const unsigned*)(rr0 + ww * RST);
                acc0 += aw * __uint_as_float(u << 16);
                acc1 += aw * __uint_as_float(u & 0xffff0000u);
            }
            float p0 = sigmoid_f(acc0), p1 = sigmoid_f(acc1);
            *(float2*)&onset_out[(size_t)s * OUTF + f] = make_float2(p0, p1);
            ushort2 o; o.x = f2bf(p0); o.y = f2bf(p1);
            *(ushort2*)&Xb[q * XST + 88 + f] = o;
        }
    }
    __syncthreads();

    // ---- Phase B: C2 = Xb @ B2 via MFMA; 14 n-tiles of 16 over 8 waves ----
    {
        const int l15 = w & 15, qd = w >> 4;
#pragma unroll
        for (int rt = 0; rt < 2; rt++) {
            const int t = q + rt * 8;
            if (t < 14) {
                const int n0 = t * 16;
                const ushort_t* bp = B2b + (size_t)(n0 + l15) * 192 + qd * 8;
                const ushort_t* ap = &Xb[l15 * XST + qd * 8];
                f32x4 acc = (f32x4){0.f, 0.f, 0.f, 0.f};
#pragma unroll
                for (int it = 0; it < 6; it++) {
                    bf16x8 av = *(const bf16x8*)(ap + it * 32);
                    bf16x8 bv = *(const bf16x8*)(bp + it * 32);
                    acc = __builtin_amdgcn_mfma_f32_16x16x32_bf16(
                        av, bv, acc, 0, 0, 0);
                }
                if (qd < 2) {                       // rows 0..7 are real
                    const int n = n0 + l15;
                    const float b2 = bias2[n];
#pragma unroll
                    for (int r = 0; r < 4; r++) {
                        const int m = qd * 4 + r;
                        float val = acc[r] + b2;
                        if (n < 128)        EHc[m * 128 + n] = __expf(val + val);
                        else if (n < NC2)   basec[m * 88 + (n - 128)] = val;
                    }
                }
            }
        }
    }
    __syncthreads();

    // ---- Phase C: frame attention (EH from LDS broadcast) ----
    {
        const ushort_t* pb = &Plc[row * EPST];
        const float* hl = &EHc[q * 128];
        float accr = 0.f;
#pragma unroll
        for (int d8 = 0; d8 < 16; d8++) {
            uint4 pv = *(const uint4*)(pb + ((d8 ^ rsw) << 3));
            float4 ha = *(const float4*)(hl + d8 * 8);
            float4 hb = *(const float4*)(hl + d8 * 8 + 4);
            float4 va = *(const float4*)(vc + d8 * 8);
            float4 vb = *(const float4*)(vc + d8 * 8 + 4);
            accr += dot8(pv, ha, hb, va, vb);
        }
        float eng = svp[1] - 2.f * accr;
        if (w >= WIN) eng = -1e30f;

        float mx = eng;
#pragma unroll
        for (int m = 32; m; m >>= 1) mx = fmaxf(mx, __shfl_xor(mx, m, 64));
        float ex = __expf(eng - mx);
        float sm = ex;
#pragma unroll
        for (int m = 32; m; m >>= 1) sm += __shfl_xor(sm, m, 64);
        float a = ex * __builtin_amdgcn_rcpf(sm);
        if (w < WIN) a_c_out[(size_t)s * WIN + w] = a;

        if (w < 44) {
            const int f = 2 * w;
            float acc0 = blc[f]     + basec[q * 88 + f];
            float acc1 = blc[f + 1] + basec[q * 88 + f + 1];
            const ushort_t* rr0 = &Ql[q * RST + f];
#pragma unroll
            for (int ww = 0; ww < WIN; ww++) {
                float aw = __uint_as_float(
                    __builtin_amdgcn_readlane(__float_as_uint(a), ww));
                unsigned u = *(const unsigned*)(rr0 + ww * RST);
                acc0 += aw * __uint_as_float(u << 16);
                acc1 += aw * __uint_as_float(u & 0xffff0000u);
            }
            float p0 = sigmoid_f(acc0), p1 = sigmoid_f(acc1);
            *(float2*)&frame_out[(size_t)s * OUTF + f] = make_float2(p0, p1);
        }
    }
}

// ---------------------------------------------------------------------------
extern "C" void kernel_launch(void* const* d_in, const int* in_sizes, int n_in,
                              void* d_out, int out_size, void* d_ws, size_t ws_size,
                              hipStream_t stream)
{
    const float* spec = (const float*)d_in[0];
    const float* Wf   = (const float*)d_in[1];
    const float* bf_  = (const float*)d_in[2];
    const float* Wao  = (const float*)d_in[3];
    const float* bao  = (const float*)d_in[4];
    const float* vo   = (const float*)d_in[5];
    const float* Wl1  = (const float*)d_in[6];
    const float* bl1  = (const float*)d_in[7];
    const float* Wac  = (const float*)d_in[8];
    const float* bac  = (const float*)d_in[9];
    const float* vc   = (const float*)d_in[10];
    const float* Wlc  = (const float*)d_in[11];
    const float* blc  = (const float*)d_in[12];

    float* out  = (float*)d_out;
    float* out0 = out;                 // frame_pred [BT,88]
    float* out1 = out + 360448;        // a_frame    [BT,61]
    float* out2 = out + 610304;        // onset_pred [BT,88]
    float* out3 = out + 970752;        // a_onset    [BT,61]
    float* out4 = out + 1220608;       // feat_pred  [BT,88]

    // Workspace layout (float offsets; u16 arrays occupy count/2 floats):
    //   sv      @ 0        (16)
    //   bias1   @ 16       (704)
    //   bias2   @ 720      (256)
    //   B1b u16 @ 976      (704*256 u16  = 90112 f)   -> ends 91088
    //   B2b u16 @ 91088    (256*192 u16  = 24576 f)   -> ends 115664
    //   EHo f32 @ 115664   (4096*128 f32 = 524288 f)  -> ends 639952
    //   EPo u16 @ 639952   (4096*128 u16 = 262144 f)  -> ends 902096
    //   EPc u16 @ 902096   (262144 f)                 -> ends 1164240
    //   Rb  u16 @ 1164240  (4096*96 u16  = 196608 f)  -> ends 1360848
    //   Qb  u16 @ 1360848  (196608 f)                 -> ends 1557456 (~6.2MB)
    float* ws = (float*)d_ws;
    float*    sv    = ws;
    float*    bias1 = ws + 16;
    float*    bias2 = ws + 720;
    ushort_t* B1b   = (ushort_t*)(ws + 976);
    ushort_t* B2b   = (ushort_t*)(ws + 91088);
    float*    EHo   = ws + 115664;
    ushort_t* EPo   = (ushort_t*)(ws + 639952);
    ushort_t* EPc   = (ushort_t*)(ws + 902096);
    ushort_t* Rb    = (ushort_t*)(ws + 1164240);
    ushort_t* Qb    = (ushort_t*)(ws + 1360848);
    (void)ws_size; (void)in_sizes; (void)n_in; (void)out_size;

    prep_kernel<<<PREP_BLOCKS, 256, 0, stream>>>(
        Wf, bf_, Wao, bao, Wl1, Wac, bac, Wlc, vo, vc,
        B1b, B2b, bias1, bias2, sv);

    gemm_mfma<8, 3><<<dim3(NP1 / 64, 64), 256, 0, stream>>>(
        spec, B1b, bias1, NC1, out4, EHo, EPo, EPc, Rb, Qb);

    attn_fused<<<BT / 8, 512, 0, stream>>>(
        EHo, EPo, Rb, EPc, Qb, out4, B2b, bias2, vo, vc, sv, bl1, blc,
        out3, out2, out1, out0);
}

// Round 4
// 115.794 us; speedup vs baseline: 1.1562x; 1.0668x over previous
//
#include <hip/hip_runtime.h>

#define NBINS 229
#define OUTF  88
#define MODEL 128
#define WSZ   30
#define WIN   61
#define TLEN  1024
#define BT    4096

#define NC1 648      // gemm1 real cols
#define NP1 704      // gemm1 padded cols (11*64)
#define NC2 216      // combine-gemm real cols

typedef short bf16x8 __attribute__((ext_vector_type(8)));
typedef float f32x4 __attribute__((ext_vector_type(4)));
typedef unsigned short ushort_t;

__device__ __forceinline__ float sigmoid_f(float x) {
    return __builtin_amdgcn_rcpf(1.f + __expf(-x));
}
__device__ __forceinline__ ushort_t f2bf(float f) {
    unsigned u = __float_as_uint(f);
    return (ushort_t)((u + 0x7fffu + ((u >> 16) & 1u)) >> 16);
}

// 8-term tanh-trick partial: sum v[d]*rcp(EH[d]*EP[d]+1), EP packed bf16 pairs
__device__ __forceinline__ float dot8(uint4 pv, float4 ha, float4 hb,
                                      float4 va, float4 vb) {
    float r;
    r  = va.x * __builtin_amdgcn_rcpf(__builtin_fmaf(ha.x, __uint_as_float(pv.x << 16), 1.f));
    r += va.y * __builtin_amdgcn_rcpf(__builtin_fmaf(ha.y, __uint_as_float(pv.x & 0xffff0000u), 1.f));
    r += va.z * __builtin_amdgcn_rcpf(__builtin_fmaf(ha.z, __uint_as_float(pv.y << 16), 1.f));
    r += va.w * __builtin_amdgcn_rcpf(__builtin_fmaf(ha.w, __uint_as_float(pv.y & 0xffff0000u), 1.f));
    r += vb.x * __builtin_amdgcn_rcpf(__builtin_fmaf(hb.x, __uint_as_float(pv.z << 16), 1.f));
    r += vb.y * __builtin_amdgcn_rcpf(__builtin_fmaf(hb.y, __uint_as_float(pv.z & 0xffff0000u), 1.f));
    r += vb.z * __builtin_amdgcn_rcpf(__builtin_fmaf(hb.z, __uint_as_float(pv.w << 16), 1.f));
    r += vb.w * __builtin_amdgcn_rcpf(__builtin_fmaf(hb.w, __uint_as_float(pv.w & 0xffff0000u), 1.f));
    return r;
}

__device__ __forceinline__ bf16x8 cvt8(f32x4 a, f32x4 b) {
    bf16x8 r;
    r[0] = (short)f2bf(a.x); r[1] = (short)f2bf(a.y);
    r[2] = (short)f2bf(a.z); r[3] = (short)f2bf(a.w);
    r[4] = (short)f2bf(b.x); r[5] = (short)f2bf(b.y);
    r[6] = (short)f2bf(b.z); r[7] = (short)f2bf(b.w);
    return r;
}
// spec rows are only 4B-aligned (229 floats) -> memcpy keeps align-4 loads
__device__ __forceinline__ bf16x8 loadA(const float* sp, int k0) {
    if (k0 > 228) return (bf16x8)(short)0;          // it=7, qd>=1: all pad
    f32x4 a, b;
    __builtin_memcpy(&a, sp + k0, 16);
    if (k0 <= 216) {
        __builtin_memcpy(&b, sp + k0 + 4, 16);
    } else {                                        // k0==224: valid 224..228
        b = (f32x4){sp[228], 0.f, 0.f, 0.f};
    }
    return cvt8(a, b);
}

// ---------------------------------------------------------------------------
// gemm_prep: MFMA bf16 GEMM1 + residual prep work, ONE kernel (no prep pass).
// Blocks [0,704): GEMM. Each block is SELF-SUFFICIENT: it gathers its own
//   64-column B-slice straight from the raw fp32 weights (coalesced: for a
//   fixed k, lanes read consecutive n within one source matrix; each thread's
//   source pointer/stride resolves once) into a 32 KiB LDS tile, bf16.
//   LDS tile layout: 16B k-chunks stored at chunk^(n&31) -> MFMA b-frag reads
//   (16 lanes, fixed chunk) hit 16 distinct chunks = conflict-free; staging
//   writes collide only n vs n+32 = 2-way = free.
//   Virtual B1 column map (n): [0,88) Wf[k][n] | [88,216) Wao[k][n-88]
//   | [216,344) Wao[k+229][n-216] | [344,472) Wac[k+176][n-344]
//   | [472,560) Wl1[k][n-472] | [560,648) Wlc[k+176][n-560] | else 0
//   A = spec fp32 -> bf16 in registers; k>=229 garbage x B=0 -> harmless.
//   XCD swizzle: e=b&7 -> rows [512e,512e+512) on XCD e.
//   Epilogue (bias inline from bfr/bao): n<88 feat fp32 | 88..216 EHo=exp(2v)
//   | 216..344 EPo bf16 | 344..472 EPc bf16 | 472..560 Rb | 560..648 Qb
// Blocks [704,896): B2b[n][k] (256x192): [0,128) Wac[k][n];
//   [128,216) Wlc[k][n-128]; pad 0.
// Block 896: bias2 ([0,128)=bac else 0) + sv[0]=sum(vo), sv[1]=sum(vc).
// ---------------------------------------------------------------------------
#define GP_BLOCKS 897

__global__ __launch_bounds__(256) void gemm_prep(
    const float* __restrict__ spec,
    const float* __restrict__ Wf,  const float* __restrict__ bfr,
    const float* __restrict__ Wao, const float* __restrict__ bao,
    const float* __restrict__ Wl1,
    const float* __restrict__ Wac, const float* __restrict__ bac,
    const float* __restrict__ Wlc,
    const float* __restrict__ vo,  const float* __restrict__ vc,
    float* __restrict__ feat, float* __restrict__ EHo_,
    ushort_t* __restrict__ EPo_, ushort_t* __restrict__ EPc_,
    ushort_t* __restrict__ Rb_,  ushort_t* __restrict__ Qb_,
    ushort_t* __restrict__ B2b, float* __restrict__ bias2,
    float* __restrict__ sv)
{
    __shared__ ushort_t B1t[64 * 256];   // 32 KiB, chunk-XOR swizzled
    __shared__ float red[4];
    const int tid = threadIdx.x;
    const int b = blockIdx.x;

    if (b < 704) {
        const int e = b & 7, kf = b >> 3;
        const int rb = (e * 8 + (kf & 7)) * 64;
        const int cb = (kf >> 3) * 64;

        // ---- stage B tile: thread = (col n, k-quarter kq) ----
        {
            const int n  = tid & 63;
            const int kq = tid >> 6;            // 0..3
            const int ng = cb + n;
            const float* srcp = nullptr; int sstr = 0;
            if (ng < 88)       { srcp = Wf  + ng;                          sstr = 88;  }
            else if (ng < 216) { srcp = Wao + (ng - 88);                   sstr = 128; }
            else if (ng < 344) { srcp = Wao + (size_t)NBINS * 128 + (ng - 216); sstr = 128; }
            else if (ng < 472) { srcp = Wac + (size_t)176 * 128 + (ng - 344);   sstr = 128; }
            else if (ng < 560) { srcp = Wl1 + (ng - 472);                  sstr = 88;  }
            else if (ng < NC1) { srcp = Wlc + (size_t)176 * 88 + (ng - 560);    sstr = 88; }
            const int n31 = n & 31;
#pragma unroll
            for (int it = 0; it < 8; it++) {
                const int k8 = kq * 8 + it * 32;
                bf16x8 vv;
#pragma unroll
                for (int j = 0; j < 8; j++) {
                    const int k = k8 + j;
                    float v = (srcp && k < NBINS) ? srcp[(size_t)k * sstr] : 0.f;
                    vv[j] = (short)f2bf(v);
                }
                const int chunk = (kq + 4 * it) ^ n31;
                *(bf16x8*)&B1t[n * 256 + chunk * 8] = vv;
            }
        }
        __syncthreads();

        // ---- K loop ----
        const int wv = tid >> 6, ln = tid & 63;
        const int l15 = ln & 15, qd = ln >> 4;
        const float* sp = spec + (size_t)(rb + wv * 16 + l15) * NBINS;

        f32x4 acc[4];
#pragma unroll
        for (int nt = 0; nt < 4; nt++) acc[nt] = (f32x4){0.f, 0.f, 0.f, 0.f};

        bf16x8 af = loadA(sp, qd * 8);
#pragma unroll
        for (int it = 0; it < 8; it++) {
            const int nk = (it + 1 < 8) ? (it + 1) * 32 : 0;
            bf16x8 an = loadA(sp, nk + qd * 8);
            const int cq = qd + 4 * it;
#pragma unroll
            for (int nt = 0; nt < 4; nt++) {
                const int nn = nt * 16 + l15;
                bf16x8 bv = *(const bf16x8*)&B1t[nn * 256 + ((cq ^ (nn & 31)) << 3)];
                acc[nt] = __builtin_amdgcn_mfma_f32_16x16x32_bf16(
                    af, bv, acc[nt], 0, 0, 0);
            }
            af = an;
        }

        // ---- epilogue ----
        const int mbase = rb + wv * 16 + qd * 4;
#pragma unroll
        for (int nt = 0; nt < 4; nt++) {
            const int n = cb + nt * 16 + l15;
            if (n < NC1) {
                const float bn = (n < 88) ? bfr[n] : (n < 216 ? bao[n - 88] : 0.f);
#pragma unroll
                for (int r = 0; r < 4; r++) {
                    const int m = mbase + r;
                    float val = acc[nt][r] + bn;
                    if (n < 88) {
                        feat[(size_t)m * 88 + n] = val;
                    } else if (n < 216) {
                        EHo_[(size_t)m * 128 + (n - 88)] = __expf(val + val);
                    } else if (n < 344) {
                        EPo_[(size_t)m * 128 + (n - 216)] = f2bf(__expf(val + val));
                    } else if (n < 472) {
                        EPc_[(size_t)m * 128 + (n - 344)] = f2bf(__expf(val + val));
                    } else if (n < 560) {
                        Rb_[(size_t)m * 96 + (n - 472)] = f2bf(val);
                    } else {
                        Qb_[(size_t)m * 96 + (n - 560)] = f2bf(val);
                    }
                }
            }
        }
    } else if (b < 896) {                           // B2b
        int idx = (b - 704) * 256 + tid;
        int n = idx / 192, k = idx - n * 192;
        float v = 0.f;
        if (k < 176 && n < NC2)
            v = (n < 128) ? Wac[k * MODEL + n] : Wlc[k * 88 + (n - 128)];
        B2b[idx] = f2bf(v);
    } else {                                        // bias2 + sv
        bias2[tid] = (tid < 128) ? bac[tid] : 0.f;
        int wid = tid >> 6, lane = tid & 63;
        const float* vp = (wid < 2) ? vo : vc;
        float val = vp[(wid & 1) * 64 + lane];
#pragma unroll
        for (int m = 32; m; m >>= 1) val += __shfl_xor(val, m, 64);
        if (lane == 0) red[wid] = val;
        __syncthreads();
        if (tid == 0) {
            sv[0] = red[0] + red[1];
            sv[1] = red[2] + red[3];
        }
    }
}

// ---------------------------------------------------------------------------
// Fused attention: attn1 (onset) + combine-GEMM + attn2 (frame) in one kernel.
// One wave per position, 8 positions / 512-thread block, XCD-swizzled.
//   Phase A: onset attention (EHo global s_load, EPo/Rb windows in LDS);
//            writes a_onset + onset_pred, deposits bf16 x-row into Xb LDS.
//   Phase B: C2 = Xb @ B2 via MFMA; n<128 -> EHc LDS fp32; else basec LDS.
//   Phase C: frame attention (EHc from LDS broadcast), writes a_frame+frame.
// Softmax WITHOUT max-subtract: |eng| <= sv + 2*sum|v| ~ 15 analytically
// (v ~ N(0,0.05^2)), exp can't overflow -> both 6-step max reductions gone.
// Plo/Plc chunk-XOR swizzle keyed on (row>>3)&7 (the 8-way-conflicting lane
// set shares row&7 but spans 8 consecutive row>>3 values).
// ---------------------------------------------------------------------------
#define EPST 136
#define RST  96
#define XST  200   // 400B row stride: 16B-aligned, rows spread over 8 banks

__global__ __launch_bounds__(512) void attn_fused(
    const float* __restrict__ EHo,
    const ushort_t* __restrict__ EPo_g,
    const ushort_t* __restrict__ Rb,
    const ushort_t* __restrict__ EPc_g,
    const ushort_t* __restrict__ Qb,
    const float* __restrict__ feat,          // [BT,88] fp32 (= out4)
    const ushort_t* __restrict__ B2b,        // [256,192] bf16 n-major
    const float* __restrict__ bias2,
    const float* __restrict__ vo, const float* __restrict__ vc,
    const float* __restrict__ svp,
    const float* __restrict__ bl1, const float* __restrict__ blc,
    float* __restrict__ a_o_out, float* __restrict__ onset_out,
    float* __restrict__ a_c_out, float* __restrict__ frame_out)
{
    __shared__ alignas(16) ushort_t Plo[68 * EPST];   // 18,496 B
    __shared__ alignas(16) ushort_t Rl [68 * RST];    // 13,056 B
    __shared__ alignas(16) ushort_t Plc[68 * EPST];   // 18,496 B
    __shared__ alignas(16) ushort_t Ql [68 * RST];    // 13,056 B
    __shared__ alignas(16) ushort_t Xb [16 * XST];    //  6,400 B
    __shared__ alignas(16) float    EHc[8 * 128];     //  4,096 B
    __shared__ alignas(16) float    basec[8 * 88];    //  2,816 B  (~76.4 KB)

    const int tid = threadIdx.x;
    const int s0 = ((blockIdx.x & 7) * 64 + (blockIdx.x >> 3)) * 8;
    const int t0 = s0 & (TLEN - 1);

    // stage EPo+EPc (68 rows x 128 bf16 each): pad rows = bf16(1.0) = exp(0)
    for (int i = tid; i < 68 * 16; i += 512) {
        int j = i >> 4, c = (i & 15) * 8;
        int cs = ((i & 15) ^ ((j >> 3) & 7)) * 8;     // swizzled chunk
        int tg = t0 + j - WSZ;
        uint4 vP = {0x3f803f80u, 0x3f803f80u, 0x3f803f80u, 0x3f803f80u};
        uint4 vC = vP;
        if ((unsigned)tg < (unsigned)TLEN) {
            vP = *(const uint4*)&EPo_g[(size_t)(s0 - WSZ + j) * 128 + c];
            vC = *(const uint4*)&EPc_g[(size_t)(s0 - WSZ + j) * 128 + c];
        }
        *(uint4*)&Plo[j * EPST + cs] = vP;
        *(uint4*)&Plc[j * EPST + cs] = vC;
    }
    // stage R+Q (68 rows x 96 bf16 each): pad rows = 0 (OOB contributes a*0)
    for (int i = tid; i < 68 * 12; i += 512) {
        int j = i / 12, c = (i - j * 12) * 8;
        int tg = t0 + j - WSZ;
        uint4 vR = {0u, 0u, 0u, 0u}, vQ = {0u, 0u, 0u, 0u};
        if ((unsigned)tg < (unsigned)TLEN) {
            vR = *(const uint4*)&Rb[(size_t)(s0 - WSZ + j) * 96 + c];
            vQ = *(const uint4*)&Qb[(size_t)(s0 - WSZ + j) * 96 + c];
        }
        *(uint4*)&Rl[j * RST + c] = vR;
        *(uint4*)&Ql[j * RST + c] = vQ;
    }
    // Xb: rows 0..7 cols 0..87 = feat bf16; everything else zero
    // (cols 88..175 filled by phase A; 176.. and rows 8..15 stay zero)
    for (int i = tid; i < 16 * XST; i += 512) {
        int r = i / XST, k = i - r * XST;
        ushort_t v = 0;
        if (r < 8 && k < 88) v = f2bf(feat[(size_t)(s0 + r) * 88 + k]);
        Xb[i] = v;
    }
    __syncthreads();

    const int q = tid >> 6;
    const int w = tid & 63;
    const int s = s0 + q;
    const int su = __builtin_amdgcn_readfirstlane(s);
    const int row = q + ((w < WIN) ? w : 0);
    const int rsw = (row >> 3) & 7;

    // ---- Phase A: onset attention ----
    {
        const ushort_t* pb = &Plo[row * EPST];
        const float* hrow = EHo + (size_t)su * 128;   // uniform -> s_load
        float accr = 0.f;
#pragma unroll
        for (int d8 = 0; d8 < 16; d8++) {
            uint4 pv = *(const uint4*)(pb + ((d8 ^ rsw) << 3));
            float4 ha = *(const float4*)(hrow + d8 * 8);
            float4 hb = *(const float4*)(hrow + d8 * 8 + 4);
            float4 va = *(const float4*)(vo + d8 * 8);
            float4 vb = *(const float4*)(vo + d8 * 8 + 4);
            accr += dot8(pv, ha, hb, va, vb);
        }
        float eng = svp[0] - 2.f * accr;
        float ex = (w < WIN) ? __expf(eng) : 0.f;
        float sm = ex;
#pragma unroll
        for (int m = 32; m; m >>= 1) sm += __shfl_xor(sm, m, 64);
        float a = ex * __builtin_amdgcn_rcpf(sm);
        if (w < WIN) a_o_out[(size_t)s * WIN + w] = a;

        if (w < 44) {
            const int f = 2 * w;
            float acc0 = bl1[f], acc1 = bl1[f + 1];
            const ushort_t* rr0 = &Rl[q * RST + f];
#pragma unroll
            for (int ww = 0; ww < WIN; ww++) {
                float aw = __uint_as_float(
                    __builtin_amdgcn_readlane(__float_as_uint(a), ww));
                unsigned u = *(const unsigned*)(rr0 + ww * RST);
                acc0 += aw * __uint_as_float(u << 16);
                acc1 += aw * __uint_as_float(u & 0xffff0000u);
            }
            float p0 = sigmoid_f(acc0), p1 = sigmoid_f(acc1);
            *(float2*)&onset_out[(size_t)s * OUTF + f] = make_float2(p0, p1);
            ushort2 o; o.x = f2bf(p0); o.y = f2bf(p1);
            *(ushort2*)&Xb[q * XST + 88 + f] = o;
        }
    }
    __syncthreads();

    // ---- Phase B: C2 = Xb @ B2 via MFMA; 14 n-tiles of 16 over 8 waves ----
    {
        const int l15 = w & 15, qd = w >> 4;
#pragma unroll
        for (int rt = 0; rt < 2; rt++) {
            const int t = q + rt * 8;
            if (t < 14) {
                const int n0 = t * 16;
                const ushort_t* bp = B2b + (size_t)(n0 + l15) * 192 + qd * 8;
                const ushort_t* ap = &Xb[l15 * XST + qd * 8];
                f32x4 acc = (f32x4){0.f, 0.f, 0.f, 0.f};
#pragma unroll
                for (int it = 0; it < 6; it++) {
                    bf16x8 av = *(const bf16x8*)(ap + it * 32);
                    bf16x8 bv = *(const bf16x8*)(bp + it * 32);
                    acc = __builtin_amdgcn_mfma_f32_16x16x32_bf16(
                        av, bv, acc, 0, 0, 0);
                }
                if (qd < 2) {                       // rows 0..7 are real
                    const int n = n0 + l15;
                    const float b2 = bias2[n];
#pragma unroll
                    for (int r = 0; r < 4; r++) {
                        const int m = qd * 4 + r;
                        float val = acc[r] + b2;
                        if (n < 128)        EHc[m * 128 + n] = __expf(val + val);
                        else if (n < NC2)   basec[m * 88 + (n - 128)] = val;
                    }
                }
            }
        }
    }
    __syncthreads();

    // ---- Phase C: frame attention (EH from LDS broadcast) ----
    {
        const ushort_t* pb = &Plc[row * EPST];
        const float* hl = &EHc[q * 128];
        float accr = 0.f;
#pragma unroll
        for (int d8 = 0; d8 < 16; d8++) {
            uint4 pv = *(const uint4*)(pb + ((d8 ^ rsw) << 3));
            float4 ha = *(const float4*)(hl + d8 * 8);
            float4 hb = *(const float4*)(hl + d8 * 8 + 4);
            float4 va = *(const float4*)(vc + d8 * 8);
            float4 vb = *(const float4*)(vc + d8 * 8 + 4);
            accr += dot8(pv, ha, hb, va, vb);
        }
        float eng = svp[1] - 2.f * accr;
        float ex = (w < WIN) ? __expf(eng) : 0.f;
        float sm = ex;
#pragma unroll
        for (int m = 32; m; m >>= 1) sm += __shfl_xor(sm, m, 64);
        float a = ex * __builtin_amdgcn_rcpf(sm);
        if (w < WIN) a_c_out[(size_t)s * WIN + w] = a;

        if (w < 44) {
            const int f = 2 * w;
            float acc0 = blc[f]     + basec[q * 88 + f];
            float acc1 = blc[f + 1] + basec[q * 88 + f + 1];
            const ushort_t* rr0 = &Ql[q * RST + f];
#pragma unroll
            for (int ww = 0; ww < WIN; ww++) {
                float aw = __uint_as_float(
                    __builtin_amdgcn_readlane(__float_as_uint(a), ww));
                unsigned u = *(const unsigned*)(rr0 + ww * RST);
                acc0 += aw * __uint_as_float(u << 16);
                acc1 += aw * __uint_as_float(u & 0xffff0000u);
            }
            float p0 = sigmoid_f(acc0), p1 = sigmoid_f(acc1);
            *(float2*)&frame_out[(size_t)s * OUTF + f] = make_float2(p0, p1);
        }
    }
}

// ---------------------------------------------------------------------------
extern "C" void kernel_launch(void* const* d_in, const int* in_sizes, int n_in,
                              void* d_out, int out_size, void* d_ws, size_t ws_size,
                              hipStream_t stream)
{
    const float* spec = (const float*)d_in[0];
    const float* Wf   = (const float*)d_in[1];
    const float* bf_  = (const float*)d_in[2];
    const float* Wao  = (const float*)d_in[3];
    const float* bao  = (const float*)d_in[4];
    const float* vo   = (const float*)d_in[5];
    const float* Wl1  = (const float*)d_in[6];
    const float* bl1  = (const float*)d_in[7];
    const float* Wac  = (const float*)d_in[8];
    const float* bac  = (const float*)d_in[9];
    const float* vc   = (const float*)d_in[10];
    const float* Wlc  = (const float*)d_in[11];
    const float* blc  = (const float*)d_in[12];

    float* out  = (float*)d_out;
    float* out0 = out;                 // frame_pred [BT,88]
    float* out1 = out + 360448;        // a_frame    [BT,61]
    float* out2 = out + 610304;        // onset_pred [BT,88]
    float* out3 = out + 970752;        // a_onset    [BT,61]
    float* out4 = out + 1220608;       // feat_pred  [BT,88]

    // Workspace layout (float offsets; u16 arrays occupy count/2 floats):
    //   sv      @ 0        (16)
    //   bias2   @ 16       (256)
    //   B2b u16 @ 272      (256*192 u16  = 24576 f)  -> ends 24848
    //   EHo f32 @ 24848    (4096*128 f32 = 524288 f) -> ends 549136
    //   EPo u16 @ 549136   (4096*128 u16 = 262144 f) -> ends 811280
    //   EPc u16 @ 811280   (262144 f)                -> ends 1073424
    //   Rb  u16 @ 1073424  (4096*96 u16  = 196608 f) -> ends 1270032
    //   Qb  u16 @ 1270032  (196608 f)                -> ends 1466640 (~5.9MB)
    float* ws = (float*)d_ws;
    float*    sv    = ws;
    float*    bias2 = ws + 16;
    ushort_t* B2b   = (ushort_t*)(ws + 272);
    float*    EHo   = ws + 24848;
    ushort_t* EPo   = (ushort_t*)(ws + 549136);
    ushort_t* EPc   = (ushort_t*)(ws + 811280);
    ushort_t* Rb    = (ushort_t*)(ws + 1073424);
    ushort_t* Qb    = (ushort_t*)(ws + 1270032);
    (void)ws_size; (void)in_sizes; (void)n_in; (void)out_size;

    gemm_prep<<<GP_BLOCKS, 256, 0, stream>>>(
        spec, Wf, bf_, Wao, bao, Wl1, Wac, bac, Wlc, vo, vc,
        out4, EHo, EPo, EPc, Rb, Qb, B2b, bias2, sv);

    attn_fused<<<BT / 8, 512, 0, stream>>>(
        EHo, EPo, Rb, EPc, Qb, out4, B2b, bias2, vo, vc, sv, bl1, blc,
        out3, out2, out1, out0);
}

// Round 7
// 111.910 us; speedup vs baseline: 1.1964x; 1.0347x over previous
//
#include <hip/hip_runtime.h>

#define NBINS 229
#define OUTF  88
#define MODEL 128
#define WSZ   30
#define WIN   61
#define TLEN  1024
#define BT    4096

#define NC1 648      // gemm1 real cols
#define NP1 704      // gemm1 padded cols (11*64)
#define NC2 216      // combine-gemm real cols

typedef short bf16x8 __attribute__((ext_vector_type(8)));
typedef float f32x4 __attribute__((ext_vector_type(4)));
typedef unsigned short ushort_t;

__device__ __forceinline__ float sigmoid_f(float x) {
    return __builtin_amdgcn_rcpf(1.f + __expf(-x));
}
__device__ __forceinline__ ushort_t f2bf(float f) {
    unsigned u = __float_as_uint(f);
    return (ushort_t)((u + 0x7fffu + ((u >> 16) & 1u)) >> 16);
}

// 8-term tanh-trick partial: sum v[d]*rcp(EH[d]*EP[d]+1), EP packed bf16 pairs
// (scalar form — VERIFIED in rounds 2-4; the pk-fma asm variant is suspect
//  and has been reverted as the round-7 bisect)
__device__ __forceinline__ float dot8(uint4 pv, float4 ha, float4 hb,
                                      float4 va, float4 vb) {
    float r;
    r  = va.x * __builtin_amdgcn_rcpf(__builtin_fmaf(ha.x, __uint_as_float(pv.x << 16), 1.f));
    r += va.y * __builtin_amdgcn_rcpf(__builtin_fmaf(ha.y, __uint_as_float(pv.x & 0xffff0000u), 1.f));
    r += va.z * __builtin_amdgcn_rcpf(__builtin_fmaf(ha.z, __uint_as_float(pv.y << 16), 1.f));
    r += va.w * __builtin_amdgcn_rcpf(__builtin_fmaf(ha.w, __uint_as_float(pv.y & 0xffff0000u), 1.f));
    r += vb.x * __builtin_amdgcn_rcpf(__builtin_fmaf(hb.x, __uint_as_float(pv.z << 16), 1.f));
    r += vb.y * __builtin_amdgcn_rcpf(__builtin_fmaf(hb.y, __uint_as_float(pv.z & 0xffff0000u), 1.f));
    r += vb.z * __builtin_amdgcn_rcpf(__builtin_fmaf(hb.z, __uint_as_float(pv.w << 16), 1.f));
    r += vb.w * __builtin_amdgcn_rcpf(__builtin_fmaf(hb.w, __uint_as_float(pv.w & 0xffff0000u), 1.f));
    return r;
}

__device__ __forceinline__ bf16x8 cvt8(f32x4 a, f32x4 b) {
    bf16x8 r;
    r[0] = (short)f2bf(a.x); r[1] = (short)f2bf(a.y);
    r[2] = (short)f2bf(a.z); r[3] = (short)f2bf(a.w);
    r[4] = (short)f2bf(b.x); r[5] = (short)f2bf(b.y);
    r[6] = (short)f2bf(b.z); r[7] = (short)f2bf(b.w);
    return r;
}
// spec rows are only 4B-aligned (229 floats) -> memcpy keeps align-4 loads
__device__ __forceinline__ bf16x8 loadA(const float* sp, int k0) {
    if (k0 > 228) return (bf16x8)(short)0;          // it=7, qd>=1: all pad
    f32x4 a, b;
    __builtin_memcpy(&a, sp + k0, 16);
    if (k0 <= 216) {
        __builtin_memcpy(&b, sp + k0 + 4, 16);
    } else {                                        // k0==224: valid 224..228
        b = (f32x4){sp[228], 0.f, 0.f, 0.f};
    }
    return cvt8(a, b);
}

// ---------------------------------------------------------------------------
// gemm_prep: MFMA bf16 GEMM1 + residual prep work, ONE kernel (unchanged from
// round 4 — verified). See round-4 comments for layout details.
// ---------------------------------------------------------------------------
#define GP_BLOCKS 897

__global__ __launch_bounds__(256) void gemm_prep(
    const float* __restrict__ spec,
    const float* __restrict__ Wf,  const float* __restrict__ bfr,
    const float* __restrict__ Wao, const float* __restrict__ bao,
    const float* __restrict__ Wl1,
    const float* __restrict__ Wac, const float* __restrict__ bac,
    const float* __restrict__ Wlc,
    const float* __restrict__ vo,  const float* __restrict__ vc,
    float* __restrict__ feat, float* __restrict__ EHo_,
    ushort_t* __restrict__ EPo_, ushort_t* __restrict__ EPc_,
    ushort_t* __restrict__ Rb_,  ushort_t* __restrict__ Qb_,
    ushort_t* __restrict__ B2b, float* __restrict__ bias2,
    float* __restrict__ sv)
{
    __shared__ ushort_t B1t[64 * 256];   // 32 KiB, chunk-XOR swizzled
    __shared__ float red[4];
    const int tid = threadIdx.x;
    const int b = blockIdx.x;

    if (b < 704) {
        const int e = b & 7, kf = b >> 3;
        const int rb = (e * 8 + (kf & 7)) * 64;
        const int cb = (kf >> 3) * 64;

        // ---- stage B tile: thread = (col n, k-quarter kq) ----
        {
            const int n  = tid & 63;
            const int kq = tid >> 6;            // 0..3
            const int ng = cb + n;
            const float* srcp = nullptr; int sstr = 0;
            if (ng < 88)       { srcp = Wf  + ng;                          sstr = 88;  }
            else if (ng < 216) { srcp = Wao + (ng - 88);                   sstr = 128; }
            else if (ng < 344) { srcp = Wao + (size_t)NBINS * 128 + (ng - 216); sstr = 128; }
            else if (ng < 472) { srcp = Wac + (size_t)176 * 128 + (ng - 344);   sstr = 128; }
            else if (ng < 560) { srcp = Wl1 + (ng - 472);                  sstr = 88;  }
            else if (ng < NC1) { srcp = Wlc + (size_t)176 * 88 + (ng - 560);    sstr = 88; }
            const int n31 = n & 31;
#pragma unroll
            for (int it = 0; it < 8; it++) {
                const int k8 = kq * 8 + it * 32;
                bf16x8 vv;
#pragma unroll
                for (int j = 0; j < 8; j++) {
                    const int k = k8 + j;
                    float v = (srcp && k < NBINS) ? srcp[(size_t)k * sstr] : 0.f;
                    vv[j] = (short)f2bf(v);
                }
                const int chunk = (kq + 4 * it) ^ n31;
                *(bf16x8*)&B1t[n * 256 + chunk * 8] = vv;
            }
        }
        __syncthreads();

        // ---- K loop ----
        const int wv = tid >> 6, ln = tid & 63;
        const int l15 = ln & 15, qd = ln >> 4;
        const float* sp = spec + (size_t)(rb + wv * 16 + l15) * NBINS;

        f32x4 acc[4];
#pragma unroll
        for (int nt = 0; nt < 4; nt++) acc[nt] = (f32x4){0.f, 0.f, 0.f, 0.f};

        bf16x8 af = loadA(sp, qd * 8);
#pragma unroll
        for (int it = 0; it < 8; it++) {
            const int nk = (it + 1 < 8) ? (it + 1) * 32 : 0;
            bf16x8 an = loadA(sp, nk + qd * 8);
            const int cq = qd + 4 * it;
#pragma unroll
            for (int nt = 0; nt < 4; nt++) {
                const int nn = nt * 16 + l15;
                bf16x8 bv = *(const bf16x8*)&B1t[nn * 256 + ((cq ^ (nn & 31)) << 3)];
                acc[nt] = __builtin_amdgcn_mfma_f32_16x16x32_bf16(
                    af, bv, acc[nt], 0, 0, 0);
            }
            af = an;
        }

        // ---- epilogue ----
        const int mbase = rb + wv * 16 + qd * 4;
#pragma unroll
        for (int nt = 0; nt < 4; nt++) {
            const int n = cb + nt * 16 + l15;
            if (n < NC1) {
                const float bn = (n < 88) ? bfr[n] : (n < 216 ? bao[n - 88] : 0.f);
#pragma unroll
                for (int r = 0; r < 4; r++) {
                    const int m = mbase + r;
                    float val = acc[nt][r] + bn;
                    if (n < 88) {
                        feat[(size_t)m * 88 + n] = val;
                    } else if (n < 216) {
                        EHo_[(size_t)m * 128 + (n - 88)] = __expf(val + val);
                    } else if (n < 344) {
                        EPo_[(size_t)m * 128 + (n - 216)] = f2bf(__expf(val + val));
                    } else if (n < 472) {
                        EPc_[(size_t)m * 128 + (n - 344)] = f2bf(__expf(val + val));
                    } else if (n < 560) {
                        Rb_[(size_t)m * 96 + (n - 472)] = f2bf(val);
                    } else {
                        Qb_[(size_t)m * 96 + (n - 560)] = f2bf(val);
                    }
                }
            }
        }
    } else if (b < 896) {                           // B2b
        int idx = (b - 704) * 256 + tid;
        int n = idx / 192, k = idx - n * 192;
        float v = 0.f;
        if (k < 176 && n < NC2)
            v = (n < 128) ? Wac[k * MODEL + n] : Wlc[k * 88 + (n - 128)];
        B2b[idx] = f2bf(v);
    } else {                                        // bias2 + sv
        bias2[tid] = (tid < 128) ? bac[tid] : 0.f;
        int wid = tid >> 6, lane = tid & 63;
        const float* vp = (wid < 2) ? vo : vc;
        float val = vp[(wid & 1) * 64 + lane];
#pragma unroll
        for (int m = 32; m; m >>= 1) val += __shfl_xor(val, m, 64);
        if (lane == 0) red[wid] = val;
        __syncthreads();
        if (tid == 0) {
            sv[0] = red[0] + red[1];
            sv[1] = red[2] + red[3];
        }
    }
}

// ---------------------------------------------------------------------------
// Fused attention. 8 positions/block (one wave each), XCD-swizzled.
//   A-dot : energies via scalar tanh trick (r4-verified), softmax (no max),
//           a_onset out + bf16 weights into amat band matrix
//   PV-A  : MFMA [16x96 amat]@[96x96 Rl] -> sigmoid -> onset_pred + Xb
//   B     : C2 = Xb @ B2 (MFMA) -> EHc / basec
//   C-dot : same as A-dot with Plc/EHc -> a_frame + amat
//   PV-C  : MFMA amat@Ql + basec -> sigmoid -> frame_pred
// K=96 MFMA reads overrun Rl/Ql rows 68..95 into the NEXT array; every byte
// of that range MUST be initialized & finite (A=0 does NOT mask NaN B:
// 0*NaN=NaN). Ql overrun -> Xb (fully written). Rl overrun -> Plc INCLUDING
// its pad cols 128..135, explicitly zeroed below. Am zeroed for all 16 rows.
// amat stride 104 u16 (208B): a-frag rows l15*52 banks -> 2-way max (free).
// ---------------------------------------------------------------------------
#define EPST 136
#define RST  96
#define XST  200
#define AST  104

#define PLO_O 0                    // 68*136 u16 = 18496 B
#define RL_O  (68 * EPST)          // byte 18496: 68*96 u16 = 13056 B
#define PLC_O (RL_O + 68 * RST)    // byte 31552
#define QL_O  (PLC_O + 68 * EPST)  // byte 50048
#define XB_O  (QL_O + 68 * RST)    // byte 63104: 16*200 u16 = 6400 B
#define AM_O  (XB_O + 16 * XST)    // byte 69504: 16*104 u16 = 3328 B
#define EHC_O (AM_O + 16 * AST)    // byte 72832: 1024 f32 = 4096 B (u16 idx)
#define BSC_O (EHC_O + 2048)       // byte 76928: 704 f32 = 2816 B
#define SH_U16 ((BSC_O + 1408))    // 39872 u16 = 79744 B total

__global__ __launch_bounds__(512) void attn_fused(
    const float* __restrict__ EHo,
    const ushort_t* __restrict__ EPo_g,
    const ushort_t* __restrict__ Rb,
    const ushort_t* __restrict__ EPc_g,
    const ushort_t* __restrict__ Qb,
    const float* __restrict__ feat,          // [BT,88] fp32 (= out4)
    const ushort_t* __restrict__ B2b,        // [256,192] bf16 n-major
    const float* __restrict__ bias2,
    const float* __restrict__ vo, const float* __restrict__ vc,
    const float* __restrict__ svp,
    const float* __restrict__ bl1, const float* __restrict__ blc,
    float* __restrict__ a_o_out, float* __restrict__ onset_out,
    float* __restrict__ a_c_out, float* __restrict__ frame_out)
{
    __shared__ alignas(16) ushort_t SH[SH_U16];
    ushort_t* Plo = SH + PLO_O;
    ushort_t* Rl  = SH + RL_O;
    ushort_t* Plc = SH + PLC_O;
    ushort_t* Ql  = SH + QL_O;
    ushort_t* Xb  = SH + XB_O;
    ushort_t* Am  = SH + AM_O;
    float*    EHc   = (float*)(SH + EHC_O);
    float*    basec = (float*)(SH + BSC_O);

    const int tid = threadIdx.x;
    const int s0 = ((blockIdx.x & 7) * 64 + (blockIdx.x >> 3)) * 8;
    const int t0 = s0 & (TLEN - 1);

    // stage EPo+EPc (68 x 128 bf16 each, chunk-XOR swizzled): pad = bf16(1.0)
    for (int i = tid; i < 68 * 16; i += 512) {
        int j = i >> 4, c = (i & 15) * 8;
        int cs = ((i & 15) ^ ((j >> 3) & 7)) * 8;
        int tg = t0 + j - WSZ;
        uint4 vP = {0x3f803f80u, 0x3f803f80u, 0x3f803f80u, 0x3f803f80u};
        uint4 vC = vP;
        if ((unsigned)tg < (unsigned)TLEN) {
            vP = *(const uint4*)&EPo_g[(size_t)(s0 - WSZ + j) * 128 + c];
            vC = *(const uint4*)&EPc_g[(size_t)(s0 - WSZ + j) * 128 + c];
        }
        *(uint4*)&Plo[j * EPST + cs] = vP;
        *(uint4*)&Plc[j * EPST + cs] = vC;
    }
    // zero Plo/Plc pad cols 128..135 (read via Rl K=96 overrun: 0*NaN=NaN!)
    for (int i = tid; i < 68; i += 512) {
        *(uint4*)&Plo[i * EPST + 128] = (uint4){0u, 0u, 0u, 0u};
        *(uint4*)&Plc[i * EPST + 128] = (uint4){0u, 0u, 0u, 0u};
    }
    // stage R+Q (68 x 96 bf16 each): pad rows = 0
    for (int i = tid; i < 68 * 12; i += 512) {
        int j = i / 12, c = (i - j * 12) * 8;
        int tg = t0 + j - WSZ;
        uint4 vR = {0u, 0u, 0u, 0u}, vQ = {0u, 0u, 0u, 0u};
        if ((unsigned)tg < (unsigned)TLEN) {
            vR = *(const uint4*)&Rb[(size_t)(s0 - WSZ + j) * 96 + c];
            vQ = *(const uint4*)&Qb[(size_t)(s0 - WSZ + j) * 96 + c];
        }
        *(uint4*)&Rl[j * RST + c] = vR;
        *(uint4*)&Ql[j * RST + c] = vQ;
    }
    // Xb rows 0..7 cols 0..87 = feat bf16; rest zero
    for (int i = tid; i < 16 * XST; i += 512) {
        int r = i / XST, k = i - r * XST;
        ushort_t v = 0;
        if (r < 8 && k < 88) v = f2bf(feat[(size_t)(s0 + r) * 88 + k]);
        Xb[i] = v;
    }
    // amat zero: ALL 16 rows, cols 0..95 (MFMA A-frag reads rows 8..15 too)
    {
        unsigned* am32 = (unsigned*)Am;
        for (int i = tid; i < 16 * 48; i += 512)
            am32[(i / 48) * 52 + (i % 48)] = 0u;
    }
    __syncthreads();

    const int q = tid >> 6;
    const int w = tid & 63;
    const int s = s0 + q;
    const int su = __builtin_amdgcn_readfirstlane(s);
    const int row = q + ((w < WIN) ? w : 0);
    const int rsw = (row >> 3) & 7;
    const int l15 = w & 15, qd = w >> 4;

    // ---- Phase A-dot: onset energies + softmax + amat ----
    {
        const ushort_t* pb = &Plo[row * EPST];
        const float* hrow = EHo + (size_t)su * 128;   // uniform -> s_load
        float accr = 0.f;
#pragma unroll
        for (int d8 = 0; d8 < 16; d8++) {
            uint4 pv = *(const uint4*)(pb + ((d8 ^ rsw) << 3));
            float4 ha = *(const float4*)(hrow + d8 * 8);
            float4 hb = *(const float4*)(hrow + d8 * 8 + 4);
            float4 va = *(const float4*)(vo + d8 * 8);
            float4 vb = *(const float4*)(vo + d8 * 8 + 4);
            accr += dot8(pv, ha, hb, va, vb);
        }
        float eng = svp[0] - 2.f * accr;
        float ex = (w < WIN) ? __expf(eng) : 0.f;
        float sm = ex;
#pragma unroll
        for (int m = 32; m; m >>= 1) sm += __shfl_xor(sm, m, 64);
        float a = ex * __builtin_amdgcn_rcpf(sm);
        if (w < WIN) {
            a_o_out[(size_t)s * WIN + w] = a;
            Am[q * AST + q + w] = f2bf(a);
        }
    }
    __syncthreads();

    // ---- PV-A: MFMA amat @ Rl -> onset_pred + Xb ----
    if (q < 6) {
        f32x4 acc = (f32x4){0.f, 0.f, 0.f, 0.f};
#pragma unroll
        for (int kk = 0; kk < 3; kk++) {
            bf16x8 av = *(const bf16x8*)&Am[l15 * AST + kk * 32 + qd * 8];
            bf16x8 bv;
#pragma unroll
            for (int j = 0; j < 8; j++)
                bv[j] = (short)Rl[(kk * 32 + qd * 8 + j) * RST + q * 16 + l15];
            acc = __builtin_amdgcn_mfma_f32_16x16x32_bf16(av, bv, acc, 0, 0, 0);
        }
        const int f = q * 16 + l15;
        if (qd < 2 && f < 88) {
            const float bb = bl1[f];
#pragma unroll
            for (int r = 0; r < 4; r++) {
                const int m = qd * 4 + r;
                float p = sigmoid_f(acc[r] + bb);
                onset_out[(size_t)(s0 + m) * OUTF + f] = p;
                Xb[m * XST + 88 + f] = f2bf(p);
            }
        }
    }
    __syncthreads();

    // ---- Phase B: C2 = Xb @ B2 via MFMA; 14 n-tiles over 8 waves ----
    {
#pragma unroll
        for (int rt = 0; rt < 2; rt++) {
            const int t = q + rt * 8;
            if (t < 14) {
                const int n0 = t * 16;
                const ushort_t* bp = B2b + (size_t)(n0 + l15) * 192 + qd * 8;
                const ushort_t* ap = &Xb[l15 * XST + qd * 8];
                f32x4 acc = (f32x4){0.f, 0.f, 0.f, 0.f};
#pragma unroll
                for (int it = 0; it < 6; it++) {
                    bf16x8 av = *(const bf16x8*)(ap + it * 32);
                    bf16x8 bv = *(const bf16x8*)(bp + it * 32);
                    acc = __builtin_amdgcn_mfma_f32_16x16x32_bf16(
                        av, bv, acc, 0, 0, 0);
                }
                if (qd < 2) {
                    const int n = n0 + l15;
                    const float b2 = bias2[n];
#pragma unroll
                    for (int r = 0; r < 4; r++) {
                        const int m = qd * 4 + r;
                        float val = acc[r] + b2;
                        if (n < 128)        EHc[m * 128 + n] = __expf(val + val);
                        else if (n < NC2)   basec[m * 88 + (n - 128)] = val;
                    }
                }
            }
        }
    }
    __syncthreads();

    // ---- Phase C-dot: frame energies + softmax + amat ----
    {
        const ushort_t* pb = &Plc[row * EPST];
        const float* hl = &EHc[q * 128];
        float accr = 0.f;
#pragma unroll
        for (int d8 = 0; d8 < 16; d8++) {
            uint4 pv = *(const uint4*)(pb + ((d8 ^ rsw) << 3));
            float4 ha = *(const float4*)(hl + d8 * 8);
            float4 hb = *(const float4*)(hl + d8 * 8 + 4);
            float4 va = *(const float4*)(vc + d8 * 8);
            float4 vb = *(const float4*)(vc + d8 * 8 + 4);
            accr += dot8(pv, ha, hb, va, vb);
        }
        float eng = svp[1] - 2.f * accr;
        float ex = (w < WIN) ? __expf(eng) : 0.f;
        float sm = ex;
#pragma unroll
        for (int m = 32; m; m >>= 1) sm += __shfl_xor(sm, m, 64);
        float a = ex * __builtin_amdgcn_rcpf(sm);
        if (w < WIN) {
            a_c_out[(size_t)s * WIN + w] = a;
            Am[q * AST + q + w] = f2bf(a);
        }
    }
    __syncthreads();

    // ---- PV-C: MFMA amat @ Ql + basec -> frame_pred ----
    if (q < 6) {
        f32x4 acc = (f32x4){0.f, 0.f, 0.f, 0.f};
#pragma unroll
        for (int kk = 0; kk < 3; kk++) {
            bf16x8 av = *(const bf16x8*)&Am[l15 * AST + kk * 32 + qd * 8];
            bf16x8 bv;
#pragma unroll
            for (int j = 0; j < 8; j++)
                bv[j] = (short)Ql[(kk * 32 + qd * 8 + j) * RST + q * 16 + l15];
            acc = __builtin_amdgcn_mfma_f32_16x16x32_bf16(av, bv, acc, 0, 0, 0);
        }
        const int f = q * 16 + l15;
        if (qd < 2 && f < 88) {
            const float bb = blc[f];
#pragma unroll
            for (int r = 0; r < 4; r++) {
                const int m = qd * 4 + r;
                float p = sigmoid_f(acc[r] + bb + basec[m * 88 + f]);
                frame_out[(size_t)(s0 + m) * OUTF + f] = p;
            }
        }
    }
}

// ---------------------------------------------------------------------------
extern "C" void kernel_launch(void* const* d_in, const int* in_sizes, int n_in,
                              void* d_out, int out_size, void* d_ws, size_t ws_size,
                              hipStream_t stream)
{
    const float* spec = (const float*)d_in[0];
    const float* Wf   = (const float*)d_in[1];
    const float* bf_  = (const float*)d_in[2];
    const float* Wao  = (const float*)d_in[3];
    const float* bao  = (const float*)d_in[4];
    const float* vo   = (const float*)d_in[5];
    const float* Wl1  = (const float*)d_in[6];
    const float* bl1  = (const float*)d_in[7];
    const float* Wac  = (const float*)d_in[8];
    const float* bac  = (const float*)d_in[9];
    const float* vc   = (const float*)d_in[10];
    const float* Wlc  = (const float*)d_in[11];
    const float* blc  = (const float*)d_in[12];

    float* out  = (float*)d_out;
    float* out0 = out;                 // frame_pred [BT,88]
    float* out1 = out + 360448;        // a_frame    [BT,61]
    float* out2 = out + 610304;        // onset_pred [BT,88]
    float* out3 = out + 970752;        // a_onset    [BT,61]
    float* out4 = out + 1220608;       // feat_pred  [BT,88]

    // Workspace layout (float offsets; u16 arrays occupy count/2 floats):
    //   sv @0 (16) | bias2 @16 (256) | B2b u16 @272 (24576f)
    //   EHo f32 @24848 (524288f) | EPo u16 @549136 (262144f)
    //   EPc u16 @811280 (262144f) | Rb u16 @1073424 (196608f)
    //   Qb u16 @1270032 (196608f) -> ends 1466640 (~5.9MB)
    float* ws = (float*)d_ws;
    float*    sv    = ws;
    float*    bias2 = ws + 16;
    ushort_t* B2b   = (ushort_t*)(ws + 272);
    float*    EHo   = ws + 24848;
    ushort_t* EPo   = (ushort_t*)(ws + 549136);
    ushort_t* EPc   = (ushort_t*)(ws + 811280);
    ushort_t* Rb    = (ushort_t*)(ws + 1073424);
    ushort_t* Qb    = (ushort_t*)(ws + 1270032);
    (void)ws_size; (void)in_sizes; (void)n_in; (void)out_size;

    gemm_prep<<<GP_BLOCKS, 256, 0, stream>>>(
        spec, Wf, bf_, Wao, bao, Wl1, Wac, bac, Wlc, vo, vc,
        out4, EHo, EPo, EPc, Rb, Qb, B2b, bias2, sv);

    attn_fused<<<BT / 8, 512, 0, stream>>>(
        EHo, EPo, Rb, EPc, Qb, out4, B2b, bias2, vo, vc, sv, bl1, blc,
        out3, out2, out1, out0);
}

// Round 8
// 111.842 us; speedup vs baseline: 1.1971x; 1.0006x over previous
//
#include <hip/hip_runtime.h>

#define NBINS 229
#define OUTF  88
#define MODEL 128
#define WSZ   30
#define WIN   61
#define TLEN  1024
#define BT    4096

#define NC1 648      // gemm1 real cols
#define NP1 704      // gemm1 padded cols (11*64)
#define NC2 216      // combine-gemm real cols

typedef short bf16x8 __attribute__((ext_vector_type(8)));
typedef float f32x4 __attribute__((ext_vector_type(4)));
typedef unsigned short ushort_t;

__device__ __forceinline__ float sigmoid_f(float x) {
    return __builtin_amdgcn_rcpf(1.f + __expf(-x));
}
__device__ __forceinline__ ushort_t f2bf(float f) {
    unsigned u = __float_as_uint(f);
    return (ushort_t)((u + 0x7fffu + ((u >> 16) & 1u)) >> 16);
}

// 8-term tanh-trick partial: sum v[d]*rcp(EH[d]*EP[d]+1), EP packed bf16 pairs
// (scalar form — verified r2-r7; do NOT reintroduce the pk-fma asm, it was
//  the round-5/6 NaN source)
__device__ __forceinline__ float dot8(uint4 pv, float4 ha, float4 hb,
                                      float4 va, float4 vb) {
    float r;
    r  = va.x * __builtin_amdgcn_rcpf(__builtin_fmaf(ha.x, __uint_as_float(pv.x << 16), 1.f));
    r += va.y * __builtin_amdgcn_rcpf(__builtin_fmaf(ha.y, __uint_as_float(pv.x & 0xffff0000u), 1.f));
    r += va.z * __builtin_amdgcn_rcpf(__builtin_fmaf(ha.z, __uint_as_float(pv.y << 16), 1.f));
    r += va.w * __builtin_amdgcn_rcpf(__builtin_fmaf(ha.w, __uint_as_float(pv.y & 0xffff0000u), 1.f));
    r += vb.x * __builtin_amdgcn_rcpf(__builtin_fmaf(hb.x, __uint_as_float(pv.z << 16), 1.f));
    r += vb.y * __builtin_amdgcn_rcpf(__builtin_fmaf(hb.y, __uint_as_float(pv.z & 0xffff0000u), 1.f));
    r += vb.z * __builtin_amdgcn_rcpf(__builtin_fmaf(hb.z, __uint_as_float(pv.w << 16), 1.f));
    r += vb.w * __builtin_amdgcn_rcpf(__builtin_fmaf(hb.w, __uint_as_float(pv.w & 0xffff0000u), 1.f));
    return r;
}

__device__ __forceinline__ bf16x8 cvt8(f32x4 a, f32x4 b) {
    bf16x8 r;
    r[0] = (short)f2bf(a.x); r[1] = (short)f2bf(a.y);
    r[2] = (short)f2bf(a.z); r[3] = (short)f2bf(a.w);
    r[4] = (short)f2bf(b.x); r[5] = (short)f2bf(b.y);
    r[6] = (short)f2bf(b.z); r[7] = (short)f2bf(b.w);
    return r;
}
// spec rows are only 4B-aligned (229 floats) -> memcpy keeps align-4 loads
__device__ __forceinline__ bf16x8 loadA(const float* sp, int k0) {
    if (k0 > 228) return (bf16x8)(short)0;          // it=7, qd>=1: all pad
    f32x4 a, b;
    __builtin_memcpy(&a, sp + k0, 16);
    if (k0 <= 216) {
        __builtin_memcpy(&b, sp + k0 + 4, 16);
    } else {                                        // k0==224: valid 224..228
        b = (f32x4){sp[228], 0.f, 0.f, 0.f};
    }
    return cvt8(a, b);
}

// ---------------------------------------------------------------------------
// gemm_prep: MFMA bf16 GEMM1 + residual prep work, ONE kernel (unchanged from
// round 4 — verified). See round-4 comments for layout details.
// ---------------------------------------------------------------------------
#define GP_BLOCKS 897

__global__ __launch_bounds__(256) void gemm_prep(
    const float* __restrict__ spec,
    const float* __restrict__ Wf,  const float* __restrict__ bfr,
    const float* __restrict__ Wao, const float* __restrict__ bao,
    const float* __restrict__ Wl1,
    const float* __restrict__ Wac, const float* __restrict__ bac,
    const float* __restrict__ Wlc,
    const float* __restrict__ vo,  const float* __restrict__ vc,
    float* __restrict__ feat, float* __restrict__ EHo_,
    ushort_t* __restrict__ EPo_, ushort_t* __restrict__ EPc_,
    ushort_t* __restrict__ Rb_,  ushort_t* __restrict__ Qb_,
    ushort_t* __restrict__ B2b, float* __restrict__ bias2,
    float* __restrict__ sv)
{
    __shared__ ushort_t B1t[64 * 256];   // 32 KiB, chunk-XOR swizzled
    __shared__ float red[4];
    const int tid = threadIdx.x;
    const int b = blockIdx.x;

    if (b < 704) {
        const int e = b & 7, kf = b >> 3;
        const int rb = (e * 8 + (kf & 7)) * 64;
        const int cb = (kf >> 3) * 64;

        // ---- stage B tile: thread = (col n, k-quarter kq) ----
        {
            const int n  = tid & 63;
            const int kq = tid >> 6;            // 0..3
            const int ng = cb + n;
            const float* srcp = nullptr; int sstr = 0;
            if (ng < 88)       { srcp = Wf  + ng;                          sstr = 88;  }
            else if (ng < 216) { srcp = Wao + (ng - 88);                   sstr = 128; }
            else if (ng < 344) { srcp = Wao + (size_t)NBINS * 128 + (ng - 216); sstr = 128; }
            else if (ng < 472) { srcp = Wac + (size_t)176 * 128 + (ng - 344);   sstr = 128; }
            else if (ng < 560) { srcp = Wl1 + (ng - 472);                  sstr = 88;  }
            else if (ng < NC1) { srcp = Wlc + (size_t)176 * 88 + (ng - 560);    sstr = 88; }
            const int n31 = n & 31;
#pragma unroll
            for (int it = 0; it < 8; it++) {
                const int k8 = kq * 8 + it * 32;
                bf16x8 vv;
#pragma unroll
                for (int j = 0; j < 8; j++) {
                    const int k = k8 + j;
                    float v = (srcp && k < NBINS) ? srcp[(size_t)k * sstr] : 0.f;
                    vv[j] = (short)f2bf(v);
                }
                const int chunk = (kq + 4 * it) ^ n31;
                *(bf16x8*)&B1t[n * 256 + chunk * 8] = vv;
            }
        }
        __syncthreads();

        // ---- K loop ----
        const int wv = tid >> 6, ln = tid & 63;
        const int l15 = ln & 15, qd = ln >> 4;
        const float* sp = spec + (size_t)(rb + wv * 16 + l15) * NBINS;

        f32x4 acc[4];
#pragma unroll
        for (int nt = 0; nt < 4; nt++) acc[nt] = (f32x4){0.f, 0.f, 0.f, 0.f};

        bf16x8 af = loadA(sp, qd * 8);
#pragma unroll
        for (int it = 0; it < 8; it++) {
            const int nk = (it + 1 < 8) ? (it + 1) * 32 : 0;
            bf16x8 an = loadA(sp, nk + qd * 8);
            const int cq = qd + 4 * it;
#pragma unroll
            for (int nt = 0; nt < 4; nt++) {
                const int nn = nt * 16 + l15;
                bf16x8 bv = *(const bf16x8*)&B1t[nn * 256 + ((cq ^ (nn & 31)) << 3)];
                acc[nt] = __builtin_amdgcn_mfma_f32_16x16x32_bf16(
                    af, bv, acc[nt], 0, 0, 0);
            }
            af = an;
        }

        // ---- epilogue ----
        const int mbase = rb + wv * 16 + qd * 4;
#pragma unroll
        for (int nt = 0; nt < 4; nt++) {
            const int n = cb + nt * 16 + l15;
            if (n < NC1) {
                const float bn = (n < 88) ? bfr[n] : (n < 216 ? bao[n - 88] : 0.f);
#pragma unroll
                for (int r = 0; r < 4; r++) {
                    const int m = mbase + r;
                    float val = acc[nt][r] + bn;
                    if (n < 88) {
                        feat[(size_t)m * 88 + n] = val;
                    } else if (n < 216) {
                        EHo_[(size_t)m * 128 + (n - 88)] = __expf(val + val);
                    } else if (n < 344) {
                        EPo_[(size_t)m * 128 + (n - 216)] = f2bf(__expf(val + val));
                    } else if (n < 472) {
                        EPc_[(size_t)m * 128 + (n - 344)] = f2bf(__expf(val + val));
                    } else if (n < 560) {
                        Rb_[(size_t)m * 96 + (n - 472)] = f2bf(val);
                    } else {
                        Qb_[(size_t)m * 96 + (n - 560)] = f2bf(val);
                    }
                }
            }
        }
    } else if (b < 896) {                           // B2b
        int idx = (b - 704) * 256 + tid;
        int n = idx / 192, k = idx - n * 192;
        float v = 0.f;
        if (k < 176 && n < NC2)
            v = (n < 128) ? Wac[k * MODEL + n] : Wlc[k * 88 + (n - 128)];
        B2b[idx] = f2bf(v);
    } else {                                        // bias2 + sv
        bias2[tid] = (tid < 128) ? bac[tid] : 0.f;
        int wid = tid >> 6, lane = tid & 63;
        const float* vp = (wid < 2) ? vo : vc;
        float val = vp[(wid & 1) * 64 + lane];
#pragma unroll
        for (int m = 32; m; m >>= 1) val += __shfl_xor(val, m, 64);
        if (lane == 0) red[wid] = val;
        __syncthreads();
        if (tid == 0) {
            sv[0] = red[0] + red[1];
            sv[1] = red[2] + red[3];
        }
    }
}

// ---------------------------------------------------------------------------
// Fused attention, QB=16 positions/block (16 waves, 1024 thr), XCD-swizzled.
// vs QB=8: amat/Xb/C2 MFMA tiles now have 16 REAL m-rows (was 8 real + 8 pad)
// -> PV-A / Phase-B / PV-C cost per position HALVES; staging volume -44%.
// Grid 256 = 1 block/CU (94 KB LDS), 16 waves/CU = same 4/SIMD occupancy.
//   A-dot : energies via scalar tanh trick, softmax (no max: |eng|<~15),
//           a_onset out + bf16 weights into amat band matrix
//   PV-A  : MFMA [16x96 amat]@[96x96 Rl] -> sigmoid -> onset_pred + Xb
//   B     : C2 = Xb @ B2 (MFMA, 14 tiles over 16 waves) -> EHc / basec
//   C-dot : same as A-dot with Plc/EHc -> a_frame + amat
//   PV-C  : MFMA amat@Ql + basec -> sigmoid -> frame_pred
// K=96 MFMA overrun contract (every overrun byte must be initialized+finite;
// A=0 does NOT mask NaN B): Rl rows 76..95 -> Plc start (fully init incl.
// explicitly-zeroed pad cols 128..135); Ql rows 76..95 -> Xb (fully written).
// Am zeroed rows 0..15 cols 0..95; band writes stay within col 75.
// ---------------------------------------------------------------------------
#define QB    16
#define ROWS  76   // QB + 2*WSZ
#define EPST 136
#define RST  96
#define XST  200
#define AST  104

#define PLO_O 0                        // 76*136 u16 = 20672 B
#define RL_O  (ROWS * EPST)            // u16 10336
#define PLC_O (RL_O + ROWS * RST)      // u16 17632
#define QL_O  (PLC_O + ROWS * EPST)    // u16 27968
#define XB_O  (QL_O + ROWS * RST)      // u16 35264: 16*200
#define AM_O  (XB_O + 16 * XST)        // u16 38464: 16*104
#define EHC_O (AM_O + 16 * AST)        // u16 40128: 16*128 f32
#define BSC_O (EHC_O + 2 * 16 * 128)   // u16 44224: 16*88 f32
#define SH_U16 (BSC_O + 2 * 16 * 88)   // 47040 u16 = 94080 B

__global__ __launch_bounds__(1024) void attn_fused(
    const float* __restrict__ EHo,
    const ushort_t* __restrict__ EPo_g,
    const ushort_t* __restrict__ Rb,
    const ushort_t* __restrict__ EPc_g,
    const ushort_t* __restrict__ Qb,
    const float* __restrict__ feat,          // [BT,88] fp32 (= out4)
    const ushort_t* __restrict__ B2b,        // [256,192] bf16 n-major
    const float* __restrict__ bias2,
    const float* __restrict__ vo, const float* __restrict__ vc,
    const float* __restrict__ svp,
    const float* __restrict__ bl1, const float* __restrict__ blc,
    float* __restrict__ a_o_out, float* __restrict__ onset_out,
    float* __restrict__ a_c_out, float* __restrict__ frame_out)
{
    __shared__ alignas(16) ushort_t SH[SH_U16];
    ushort_t* Plo = SH + PLO_O;
    ushort_t* Rl  = SH + RL_O;
    ushort_t* Plc = SH + PLC_O;
    ushort_t* Ql  = SH + QL_O;
    ushort_t* Xb  = SH + XB_O;
    ushort_t* Am  = SH + AM_O;
    float*    EHc   = (float*)(SH + EHC_O);
    float*    basec = (float*)(SH + BSC_O);

    const int tid = threadIdx.x;
    const int s0 = ((blockIdx.x & 7) * 32 + (blockIdx.x >> 3)) * QB;
    const int t0 = s0 & (TLEN - 1);

    // stage EPo+EPc (76 x 128 bf16 each, chunk-XOR swizzled): pad = bf16(1.0)
    for (int i = tid; i < ROWS * 16; i += 1024) {
        int j = i >> 4, c = (i & 15) * 8;
        int cs = ((i & 15) ^ ((j >> 3) & 7)) * 8;
        int tg = t0 + j - WSZ;
        uint4 vP = {0x3f803f80u, 0x3f803f80u, 0x3f803f80u, 0x3f803f80u};
        uint4 vC = vP;
        if ((unsigned)tg < (unsigned)TLEN) {
            vP = *(const uint4*)&EPo_g[(size_t)(s0 - WSZ + j) * 128 + c];
            vC = *(const uint4*)&EPc_g[(size_t)(s0 - WSZ + j) * 128 + c];
        }
        *(uint4*)&Plo[j * EPST + cs] = vP;
        *(uint4*)&Plc[j * EPST + cs] = vC;
    }
    // zero Plo/Plc pad cols 128..135 (read via Rl K=96 overrun: 0*NaN=NaN!)
    for (int i = tid; i < ROWS; i += 1024) {
        *(uint4*)&Plo[i * EPST + 128] = (uint4){0u, 0u, 0u, 0u};
        *(uint4*)&Plc[i * EPST + 128] = (uint4){0u, 0u, 0u, 0u};
    }
    // stage R+Q (76 x 96 bf16 each): pad rows = 0
    for (int i = tid; i < ROWS * 12; i += 1024) {
        int j = i / 12, c = (i - j * 12) * 8;
        int tg = t0 + j - WSZ;
        uint4 vR = {0u, 0u, 0u, 0u}, vQ = {0u, 0u, 0u, 0u};
        if ((unsigned)tg < (unsigned)TLEN) {
            vR = *(const uint4*)&Rb[(size_t)(s0 - WSZ + j) * 96 + c];
            vQ = *(const uint4*)&Qb[(size_t)(s0 - WSZ + j) * 96 + c];
        }
        *(uint4*)&Rl[j * RST + c] = vR;
        *(uint4*)&Ql[j * RST + c] = vQ;
    }
    // Xb: 16 rows; cols 0..87 = feat bf16 (ALL rows real now); rest zero
    for (int i = tid; i < 16 * XST; i += 1024) {
        int r = i / XST, k = i - r * XST;
        ushort_t v = 0;
        if (k < 88) v = f2bf(feat[(size_t)(s0 + r) * 88 + k]);
        Xb[i] = v;
    }
    // amat zero: ALL 16 rows, cols 0..95
    {
        unsigned* am32 = (unsigned*)Am;
        for (int i = tid; i < 16 * 48; i += 1024)
            am32[(i / 48) * 52 + (i % 48)] = 0u;
    }
    __syncthreads();

    const int q = tid >> 6;              // 0..15: position within block
    const int w = tid & 63;
    const int s = s0 + q;
    const int su = __builtin_amdgcn_readfirstlane(s);
    const int row = q + ((w < WIN) ? w : 0);   // 0..75
    const int rsw = (row >> 3) & 7;
    const int l15 = w & 15, qd = w >> 4;

    // ---- Phase A-dot: onset energies + softmax + amat ----
    {
        const ushort_t* pb = &Plo[row * EPST];
        const float* hrow = EHo + (size_t)su * 128;   // uniform -> s_load
        float accr = 0.f;
#pragma unroll
        for (int d8 = 0; d8 < 16; d8++) {
            uint4 pv = *(const uint4*)(pb + ((d8 ^ rsw) << 3));
            float4 ha = *(const float4*)(hrow + d8 * 8);
            float4 hb = *(const float4*)(hrow + d8 * 8 + 4);
            float4 va = *(const float4*)(vo + d8 * 8);
            float4 vb = *(const float4*)(vo + d8 * 8 + 4);
            accr += dot8(pv, ha, hb, va, vb);
        }
        float eng = svp[0] - 2.f * accr;
        float ex = (w < WIN) ? __expf(eng) : 0.f;
        float sm = ex;
#pragma unroll
        for (int m = 32; m; m >>= 1) sm += __shfl_xor(sm, m, 64);
        float a = ex * __builtin_amdgcn_rcpf(sm);
        if (w < WIN) {
            a_o_out[(size_t)s * WIN + w] = a;
            Am[q * AST + q + w] = f2bf(a);
        }
    }
    __syncthreads();

    // ---- PV-A: MFMA amat @ Rl -> onset_pred + Xb (all 16 m-rows real) ----
    if (q < 6) {
        f32x4 acc = (f32x4){0.f, 0.f, 0.f, 0.f};
#pragma unroll
        for (int kk = 0; kk < 3; kk++) {
            bf16x8 av = *(const bf16x8*)&Am[l15 * AST + kk * 32 + qd * 8];
            bf16x8 bv;
#pragma unroll
            for (int j = 0; j < 8; j++)
                bv[j] = (short)Rl[(kk * 32 + qd * 8 + j) * RST + q * 16 + l15];
            acc = __builtin_amdgcn_mfma_f32_16x16x32_bf16(av, bv, acc, 0, 0, 0);
        }
        const int f = q * 16 + l15;
        if (f < 88) {
            const float bb = bl1[f];
#pragma unroll
            for (int r = 0; r < 4; r++) {
                const int m = qd * 4 + r;
                float p = sigmoid_f(acc[r] + bb);
                onset_out[(size_t)(s0 + m) * OUTF + f] = p;
                Xb[m * XST + 88 + f] = f2bf(p);
            }
        }
    }
    __syncthreads();

    // ---- Phase B: C2 = Xb @ B2 via MFMA; 14 n-tiles over 16 waves ----
    if (q < 14) {
        const int n0 = q * 16;
        const ushort_t* bp = B2b + (size_t)(n0 + l15) * 192 + qd * 8;
        const ushort_t* ap = &Xb[l15 * XST + qd * 8];
        f32x4 acc = (f32x4){0.f, 0.f, 0.f, 0.f};
#pragma unroll
        for (int it = 0; it < 6; it++) {
            bf16x8 av = *(const bf16x8*)(ap + it * 32);
            bf16x8 bv = *(const bf16x8*)(bp + it * 32);
            acc = __builtin_amdgcn_mfma_f32_16x16x32_bf16(av, bv, acc, 0, 0, 0);
        }
        const int n = n0 + l15;
        const float b2 = bias2[n];
#pragma unroll
        for (int r = 0; r < 4; r++) {
            const int m = qd * 4 + r;
            float val = acc[r] + b2;
            if (n < 128)        EHc[m * 128 + n] = __expf(val + val);
            else if (n < NC2)   basec[m * 88 + (n - 128)] = val;
        }
    }
    __syncthreads();

    // ---- Phase C-dot: frame energies + softmax + amat ----
    {
        const ushort_t* pb = &Plc[row * EPST];
        const float* hl = &EHc[q * 128];
        float accr = 0.f;
#pragma unroll
        for (int d8 = 0; d8 < 16; d8++) {
            uint4 pv = *(const uint4*)(pb + ((d8 ^ rsw) << 3));
            float4 ha = *(const float4*)(hl + d8 * 8);
            float4 hb = *(const float4*)(hl + d8 * 8 + 4);
            float4 va = *(const float4*)(vc + d8 * 8);
            float4 vb = *(const float4*)(vc + d8 * 8 + 4);
            accr += dot8(pv, ha, hb, va, vb);
        }
        float eng = svp[1] - 2.f * accr;
        float ex = (w < WIN) ? __expf(eng) : 0.f;
        float sm = ex;
#pragma unroll
        for (int m = 32; m; m >>= 1) sm += __shfl_xor(sm, m, 64);
        float a = ex * __builtin_amdgcn_rcpf(sm);
        if (w < WIN) {
            a_c_out[(size_t)s * WIN + w] = a;
            Am[q * AST + q + w] = f2bf(a);
        }
    }
    __syncthreads();

    // ---- PV-C: MFMA amat @ Ql + basec -> frame_pred (16 m-rows real) ----
    if (q < 6) {
        f32x4 acc = (f32x4){0.f, 0.f, 0.f, 0.f};
#pragma unroll
        for (int kk = 0; kk < 3; kk++) {
            bf16x8 av = *(const bf16x8*)&Am[l15 * AST + kk * 32 + qd * 8];
            bf16x8 bv;
#pragma unroll
            for (int j = 0; j < 8; j++)
                bv[j] = (short)Ql[(kk * 32 + qd * 8 + j) * RST + q * 16 + l15];
            acc = __builtin_amdgcn_mfma_f32_16x16x32_bf16(av, bv, acc, 0, 0, 0);
        }
        const int f = q * 16 + l15;
        if (f < 88) {
            const float bb = blc[f];
#pragma unroll
            for (int r = 0; r < 4; r++) {
                const int m = qd * 4 + r;
                float p = sigmoid_f(acc[r] + bb + basec[m * 88 + f]);
                frame_out[(size_t)(s0 + m) * OUTF + f] = p;
            }
        }
    }
}

// ---------------------------------------------------------------------------
extern "C" void kernel_launch(void* const* d_in, const int* in_sizes, int n_in,
                              void* d_out, int out_size, void* d_ws, size_t ws_size,
                              hipStream_t stream)
{
    const float* spec = (const float*)d_in[0];
    const float* Wf   = (const float*)d_in[1];
    const float* bf_  = (const float*)d_in[2];
    const float* Wao  = (const float*)d_in[3];
    const float* bao  = (const float*)d_in[4];
    const float* vo   = (const float*)d_in[5];
    const float* Wl1  = (const float*)d_in[6];
    const float* bl1  = (const float*)d_in[7];
    const float* Wac  = (const float*)d_in[8];
    const float* bac  = (const float*)d_in[9];
    const float* vc   = (const float*)d_in[10];
    const float* Wlc  = (const float*)d_in[11];
    const float* blc  = (const float*)d_in[12];

    float* out  = (float*)d_out;
    float* out0 = out;                 // frame_pred [BT,88]
    float* out1 = out + 360448;        // a_frame    [BT,61]
    float* out2 = out + 610304;        // onset_pred [BT,88]
    float* out3 = out + 970752;        // a_onset    [BT,61]
    float* out4 = out + 1220608;       // feat_pred  [BT,88]

    // Workspace layout (float offsets; u16 arrays occupy count/2 floats):
    //   sv @0 (16) | bias2 @16 (256) | B2b u16 @272 (24576f)
    //   EHo f32 @24848 (524288f) | EPo u16 @549136 (262144f)
    //   EPc u16 @811280 (262144f) | Rb u16 @1073424 (196608f)
    //   Qb u16 @1270032 (196608f) -> ends 1466640 (~5.9MB)
    float* ws = (float*)d_ws;
    float*    sv    = ws;
    float*    bias2 = ws + 16;
    ushort_t* B2b   = (ushort_t*)(ws + 272);
    float*    EHo   = ws + 24848;
    ushort_t* EPo   = (ushort_t*)(ws + 549136);
    ushort_t* EPc   = (ushort_t*)(ws + 811280);
    ushort_t* Rb    = (ushort_t*)(ws + 1073424);
    ushort_t* Qb    = (ushort_t*)(ws + 1270032);
    (void)ws_size; (void)in_sizes; (void)n_in; (void)out_size;

    gemm_prep<<<GP_BLOCKS, 256, 0, stream>>>(
        spec, Wf, bf_, Wao, bao, Wl1, Wac, bac, Wlc, vo, vc,
        out4, EHo, EPo, EPc, Rb, Qb, B2b, bias2, sv);

    attn_fused<<<BT / QB, 1024, 0, stream>>>(
        EHo, EPo, Rb, EPc, Qb, out4, B2b, bias2, vo, vc, sv, bl1, blc,
        out3, out2, out1, out0);
}